// Round 3
// baseline (1607.077 us; speedup 1.0000x reference)
//
#include <hip/hip_runtime.h>

typedef unsigned short u16;
typedef unsigned int u32;
typedef __attribute__((ext_vector_type(8))) short bf16x8;
typedef __attribute__((ext_vector_type(4))) float f32x4;

#define N_NODES 50000
#define N_EDGES 800000

__device__ __forceinline__ float bf2f(u16 u) {
    union { u32 i; float f; } v; v.i = ((u32)u) << 16; return v.f;
}
__device__ __forceinline__ u16 f2bf(float f) {
    union { u32 i; float f; } v; v.f = f;
    u32 i = v.i;
    return (u16)((i + 0x7FFFu + ((i >> 16) & 1u)) >> 16);
}
// dtype-agnostic load: fl!=0 -> float32 buffer, else bf16 (u16) buffer
__device__ __forceinline__ float ldf(const void* p, int i, int fl) {
    return fl ? ((const float*)p)[i] : bf2f(((const u16*)p)[i]);
}
__device__ __forceinline__ int getflag(const int* flag) {
    return __builtin_amdgcn_readfirstlane(*flag);
}

// ---------------- dtype detection ----------------
__global__ void k_detect(const u16* __restrict__ xr, int* __restrict__ flag) {
    __shared__ int sc[256];
    int t = threadIdx.x;
    int c = 0;
    for (int i = t; i < 4096; i += 256) {
        u32 e = (xr[i] >> 7) & 0xFF;
        if (e >= 143) c++;
    }
    sc[t] = c;
    __syncthreads();
    for (int s = 128; s > 0; s >>= 1) {
        if (t < s) sc[t] += sc[t + s];
        __syncthreads();
    }
    if (t == 0) *flag = (sc[0] > 64) ? 1 : 0;   // 1 = float32, 0 = bf16
}

__global__ void k_canon_ea(const void* __restrict__ ea, float* __restrict__ eaf,
                           const int* __restrict__ flag) {
    int fl = getflag(flag);
    int e = blockIdx.x * 256 + threadIdx.x;
    if (e < N_EDGES) eaf[e] = ldf(ea, e, fl);
}

// ---------------- weight prep ----------------
struct P8 { const void* s[8]; };

__global__ void k_transpose8(P8 p, u16* __restrict__ dst0, u16* __restrict__ dst1,
                             const int* __restrict__ flag) {
    int fl = getflag(flag);
    int gid = blockIdx.x * 256 + threadIdx.x;   // 512 blocks -> 8 * 16384
    int wi = gid >> 14;
    int id = gid & 16383;
    int k = id >> 7, n = id & 127;
    u16* d = (wi < 4) ? (dst0 + wi * 16384) : (dst1 + (wi - 4) * 16384);
    d[n * 128 + k] = f2bf(ldf(p.s[wi], id, fl));
}

__global__ void k_bcat8(P8 p, float* __restrict__ out1, float* __restrict__ out2,
                        const int* __restrict__ flag) {
    int fl = getflag(flag);
    int t = blockIdx.x * 256 + threadIdx.x;   // 4 blocks -> 1024
    float v = ldf(p.s[t >> 7], t & 127, fl);
    if (t < 512) out1[t] = v; else out2[t - 512] = v;
}

// G = diag(lng)*W2 folded; csum[n] = sum_f G[f,n]; bwp[n] = sum_f lnb_f*W2[f,n] + b2[n]
__global__ void k_prep_w2(const void* __restrict__ w2, const void* __restrict__ lng_,
                          const void* __restrict__ lnb_, const void* __restrict__ b2_,
                          u16* __restrict__ gt, float* __restrict__ csum,
                          float* __restrict__ bwp, const int* __restrict__ flag)
{
    int fl = getflag(flag);
    int t = threadIdx.x;   // 128 threads, 1 block; t = output column n
    if (t < 128) {
        float cs = 0.f, bw = 0.f;
        for (int f = 0; f < 128; f++) {
            float wv = ldf(w2, f * 128 + t, fl);
            float g = ldf(lng_, f, fl);
            float b = ldf(lnb_, f, fl);
            u16 gwq = f2bf(g * wv);
            gt[t * 128 + f] = gwq;
            cs += bf2f(gwq);
            bw = fmaf(b, wv, bw);
        }
        csum[t] = cs;
        bwp[t] = bw + ldf(b2_, t, fl);
    }
}

// ---------------- embed: node-side lin1  y = x @ W1[:64] + b1 ----------------
__global__ __launch_bounds__(256) void k_embed_lin1(
    const void* __restrict__ x, const void* __restrict__ w1,
    const void* __restrict__ b1, float* __restrict__ y,
    const int* __restrict__ flag)
{
    __shared__ float sx[2][64];
    int fl = getflag(flag);
    int t = threadIdx.x;
    int col = t & 127, half = t >> 7;
    float wreg[64];
    #pragma unroll
    for (int k = 0; k < 64; k++) wreg[k] = ldf(w1, k * 128 + col, fl);
    float bias = ldf(b1, col, fl);
    int base = blockIdx.x * 64;
    for (int it = 0; it < 32; ++it) {
        __syncthreads();
        if (t < 128) {
            int nh = base + it * 2 + (t >> 6);
            sx[t >> 6][t & 63] = (nh < N_NODES) ? ldf(x, nh * 64 + (t & 63), fl) : 0.f;
        }
        __syncthreads();
        float acc = bias;
        #pragma unroll
        for (int k = 0; k < 64; k++) acc = fmaf(sx[half][k], wreg[k], acc);
        int n = base + it * 2 + half;
        if (n < N_NODES) y[(size_t)n * 128 + col] = acc;
    }
}

// ---------------- CSR build ----------------
__global__ void k_degree(const int* __restrict__ dst, int* __restrict__ cnt) {
    int e = blockIdx.x * 256 + threadIdx.x;
    if (e < N_EDGES) atomicAdd(&cnt[dst[e]], 1);
}

__global__ __launch_bounds__(1024) void k_scan(const int* __restrict__ cnt,
                                               int* __restrict__ row_start,
                                               int* __restrict__ nxt)
{
    __shared__ int wsum[16];
    __shared__ int s_tot;
    int t = threadIdx.x, lane = t & 63, wid = t >> 6;
    int run = 0;
    for (int base = 0; base < N_NODES; base += 8192) {
        int i0 = base + t * 8;
        int v[8], pre[8];
        int s = 0;
        #pragma unroll
        for (int j = 0; j < 8; j++) {
            int i = i0 + j;
            v[j] = (i < N_NODES) ? cnt[i] : 0;
            pre[j] = s;
            s += v[j];
        }
        int tsum = s;
        int sc = tsum;
        #pragma unroll
        for (int off = 1; off < 64; off <<= 1) {
            int o = __shfl_up(sc, off);
            if (lane >= off) sc += o;
        }
        if (lane == 63) wsum[wid] = sc;
        __syncthreads();
        if (t == 0) {
            int acc2 = 0;
            #pragma unroll
            for (int k2 = 0; k2 < 16; k2++) { int vv = wsum[k2]; wsum[k2] = acc2; acc2 += vv; }
            s_tot = acc2;
        }
        __syncthreads();
        int texcl = run + wsum[wid] + (sc - tsum);
        #pragma unroll
        for (int j = 0; j < 8; j++) {
            int i = i0 + j;
            if (i < N_NODES) { int ex = texcl + pre[j]; row_start[i] = ex; nxt[i] = ex; }
        }
        run += s_tot;
        __syncthreads();
    }
    if (t == 0) row_start[N_NODES] = run;
}

__global__ void k_scatter(const int* __restrict__ dst, int* __restrict__ nxt,
                          int* __restrict__ eids) {
    int e = blockIdx.x * 256 + threadIdx.x;
    if (e < N_EDGES) { int p = atomicAdd(&nxt[dst[e]], 1); eids[p] = e; }
}

// ---------------- embed: wave-per-node per-edge MLP, register aggregation ----------------
// LN1 affine folded into B (G = diag(g)W2): C = rs*(A_relu@G - mu*csum) + bwp
// LN2 affine folded out of aggregation: h = g*(sum rs2*z - sum rs2*mu2) + deg*b
__global__ __launch_bounds__(256, 4) void k_embed_edges(
    const float* __restrict__ y,
    const int* __restrict__ srcp, const float* __restrict__ eaf,
    const int* __restrict__ rowst, const int* __restrict__ eids,
    const void* __restrict__ w1, const void* __restrict__ lng, const void* __restrict__ lnb,
    const u16* __restrict__ gt, const float* __restrict__ csum, const float* __restrict__ bwp,
    float* __restrict__ h1, const int* __restrict__ flag)
{
    __shared__ u16 sB[128 * 136];   // G^T, padded rows (2-way bank conflict = free)
    int fl = getflag(flag);
    int t = threadIdx.x;
    for (int c = t; c < 128 * 32; c += 256) {
        int row = c >> 5, ch = c & 31;
        *(ushort4*)&sB[row * 136 + ch * 4] = *(const ushort4*)&gt[row * 128 + ch * 4];
    }
    int l = t & 63, w = t >> 6;
    int m = l & 15, q = l >> 4;

    // packed-bf16 W1 edge row, features f = kb*32 + q*8 + j
    u32 w1p[4][4];
    #pragma unroll
    for (int kb = 0; kb < 4; kb++)
        #pragma unroll
        for (int jj = 0; jj < 4; jj++) {
            int f = kb * 32 + q * 8 + jj * 2;
            w1p[kb][jj] = (u32)f2bf(ldf(w1, 64 * 128 + f, fl)) |
                          ((u32)f2bf(ldf(w1, 64 * 128 + f + 1, fl)) << 16);
        }
    float csum_r[8], bwp_r[8];
    #pragma unroll
    for (int nb = 0; nb < 8; nb++) {
        csum_r[nb] = csum[nb * 16 + m];
        bwp_r[nb]  = bwp[nb * 16 + m];
    }
    __syncthreads();

    int node = blockIdx.x * 4 + w;   // 12500 * 4 == N exactly
    int rs = rowst[node], re = rowst[node + 1];
    float hacc[8];
    #pragma unroll
    for (int nb = 0; nb < 8; nb++) hacc[nb] = 0.f;
    float V = 0.f;
    f32x4 zf = {0.f, 0.f, 0.f, 0.f};

    for (int base = rs; base < re; base += 16) {
        int idx = base + m;
        int eidx = (idx < re) ? idx : (re - 1);
        int eid = eids[eidx];
        int srcn = srcp[eid];
        float av = eaf[eid];

        const float* yrow = y + (size_t)srcn * 128 + q * 8;
        bf16x8 afrag[4];
        float s1 = 0.f, s2 = 0.f;
        #pragma unroll
        for (int kb = 0; kb < 4; kb++) {
            const float4* p = (const float4*)(yrow + kb * 32);
            float4 u0 = p[0], u1 = p[1];
            float tv[8] = {u0.x, u0.y, u0.z, u0.w, u1.x, u1.y, u1.z, u1.w};
            #pragma unroll
            for (int j = 0; j < 8; j++) {
                float wv = bf2f((u16)((w1p[kb][j >> 1] >> ((j & 1) * 16)) & 0xffff));
                float vv = fmaxf(fmaf(av, wv, tv[j]), 0.f);
                s1 += vv; s2 = fmaf(vv, vv, s2);
                afrag[kb][j] = (short)f2bf(vv);
            }
        }
        s1 += __shfl_xor(s1, 16); s2 += __shfl_xor(s2, 16);
        s1 += __shfl_xor(s1, 32); s2 += __shfl_xor(s2, 32);
        float mu = s1 * (1.f / 128.f);
        float rsd = rsqrtf(s2 * (1.f / 128.f) - mu * mu + 1e-5f);

        f32x4 acc[8];
        #pragma unroll
        for (int nb = 0; nb < 8; nb++) acc[nb] = zf;
        #pragma unroll
        for (int nb = 0; nb < 8; nb++) {
            const u16* brow = &sB[(nb * 16 + m) * 136 + q * 8];
            #pragma unroll
            for (int kb = 0; kb < 4; kb++) {
                bf16x8 bfrag = *(const bf16x8*)(brow + kb * 32);
                acc[nb] = __builtin_amdgcn_mfma_f32_16x16x32_bf16(afrag[kb], bfrag, acc[nb], 0, 0, 0);
            }
        }
        // per-edge epilogue: C -> relu -> LN2 stats -> masked accumulate
        #pragma unroll
        for (int r = 0; r < 4; r++) {
            int e = q * 4 + r;
            float murow = __shfl(mu, e);
            float rsrow = __shfl(rsd, e);
            float z[8]; float t1 = 0.f, t2 = 0.f;
            #pragma unroll
            for (int nb = 0; nb < 8; nb++) {
                float cval = fmaf(rsrow, fmaf(-murow, csum_r[nb], acc[nb][r]), bwp_r[nb]);
                float zz = fmaxf(cval, 0.f);
                z[nb] = zz; t1 += zz; t2 = fmaf(zz, zz, t2);
            }
            #pragma unroll
            for (int o = 1; o < 16; o <<= 1) { t1 += __shfl_xor(t1, o); t2 += __shfl_xor(t2, o); }
            float mu2 = t1 * (1.f / 128.f);
            float rs2 = rsqrtf(t2 * (1.f / 128.f) - mu2 * mu2 + 1e-5f);
            if (base + e >= re) rs2 = 0.f;   // mask pad edges
            V = fmaf(mu2, rs2, V);
            #pragma unroll
            for (int nb = 0; nb < 8; nb++) hacc[nb] = fmaf(rs2, z[nb], hacc[nb]);
        }
    }
    // cross-quad reduce and single store
    #pragma unroll
    for (int nb = 0; nb < 8; nb++) {
        hacc[nb] += __shfl_xor(hacc[nb], 16);
        hacc[nb] += __shfl_xor(hacc[nb], 32);
    }
    V += __shfl_xor(V, 16); V += __shfl_xor(V, 32);
    if (q == 0) {
        float dg = (float)(re - rs);
        #pragma unroll
        for (int nb = 0; nb < 8; nb++) {
            int f2 = nb * 16 + m;
            float gg = ldf(lng, f2, fl), bb = ldf(lnb, f2, fl);
            h1[(size_t)node * 128 + f2] = fmaf(gg, hacc[nb] - V, dg * bb);
        }
    }
}

// ---------------- fused q/k/v/skip projection GEMM ----------------
__global__ __launch_bounds__(256) void k_proj(
    const float* __restrict__ hin, const u16* __restrict__ wt,
    const float* __restrict__ bcat, u16* __restrict__ outp)
{
    __shared__ u16 sA[64 * 136];
    __shared__ u16 sB[128 * 136];
    int t = threadIdx.x;
    int l = t & 63, w = t >> 6;
    int m = l & 15, q = l >> 4;
    int rowbase = blockIdx.x * 64;
    for (int c = t; c < 64 * 32; c += 256) {
        int row = c >> 5, ch = c & 31;
        int gr = rowbase + row;
        float4 v;
        if (gr < N_NODES) v = *(const float4*)&hin[(size_t)gr * 128 + ch * 4];
        else v = make_float4(0.f, 0.f, 0.f, 0.f);
        ushort4 pk;
        pk.x = f2bf(v.x); pk.y = f2bf(v.y); pk.z = f2bf(v.z); pk.w = f2bf(v.w);
        *(ushort4*)&sA[row * 136 + ch * 4] = pk;
    }
    __syncthreads();
    bf16x8 afrag[4];
    #pragma unroll
    for (int kb = 0; kb < 4; kb++)
        afrag[kb] = *(const bf16x8*)&sA[(w * 16 + m) * 136 + kb * 32 + q * 8];

    f32x4 zf = {0.f, 0.f, 0.f, 0.f};
    for (int g = 0; g < 4; ++g) {
        __syncthreads();
        for (int c = t; c < 128 * 32; c += 256) {
            int row = c >> 5, ch = c & 31;
            *(ushort4*)&sB[row * 136 + ch * 4] = *(const ushort4*)&wt[(g * 128 + row) * 128 + ch * 4];
        }
        __syncthreads();
        f32x4 acc[8];
        #pragma unroll
        for (int nb = 0; nb < 8; nb++) acc[nb] = zf;
        #pragma unroll
        for (int nb = 0; nb < 8; nb++) {
            const u16* brow = &sB[(nb * 16 + m) * 136 + q * 8];
            #pragma unroll
            for (int kb = 0; kb < 4; kb++) {
                bf16x8 bfrag = *(const bf16x8*)(brow + kb * 32);
                acc[nb] = __builtin_amdgcn_mfma_f32_16x16x32_bf16(afrag[kb], bfrag, acc[nb], 0, 0, 0);
            }
        }
        #pragma unroll
        for (int nb = 0; nb < 8; nb++) {
            int col = g * 128 + nb * 16 + m;
            float bb = bcat[col];
            #pragma unroll
            for (int r = 0; r < 4; r++) {
                int row = rowbase + w * 16 + q * 4 + r;
                if (row < N_NODES) outp[(size_t)row * 512 + col] = f2bf(acc[nb][r] + bb);
            }
        }
    }
}

// ---------------- attention: wave per dst node, online softmax over in-edges ----------------
__global__ __launch_bounds__(256) void k_attn(
    const u16* __restrict__ qkvs,
    const int* __restrict__ rowst, const int* __restrict__ eids,
    const int* __restrict__ srcp, const float* __restrict__ eaf,
    const void* __restrict__ wep, float* __restrict__ hout,
    const int* __restrict__ flag)
{
    int fl = getflag(flag);
    int t = threadIdx.x;
    int l = t & 63, w = t >> 6;
    int dstn = blockIdx.x * 4 + w;        // grid*4 == N exactly
    int f0 = l * 2;                       // features 2l, 2l+1; head = l>>4
    u32 qu = *(const u32*)&qkvs[(size_t)dstn * 512 + f0];
    const float scale = 0.17677669529663687f;  // 1/sqrt(32)
    float q0 = bf2f((u16)(qu & 0xffff)) * scale;
    float q1 = bf2f((u16)(qu >> 16)) * scale;
    float we0 = ldf(wep, f0, fl);
    float we1 = ldf(wep, f0 + 1, fl);
    float mi = -INFINITY, si = 0.f, a0 = 0.f, a1 = 0.f;
    int rs = rowst[dstn], re = rowst[dstn + 1];
    // 1-stage software pipeline on the index chain
    int sn = 0; float av = 0.f;
    if (rs < re) { int e0 = eids[rs]; sn = srcp[e0]; av = eaf[e0]; }
    for (int i = rs; i < re; ++i) {
        int sn2 = sn; float av2 = av;
        if (i + 1 < re) { int e1 = eids[i + 1]; sn = srcp[e1]; av = eaf[e1]; }
        const u16* srow = &qkvs[(size_t)sn2 * 512 + f0];
        u32 ku = *(const u32*)(srow + 128);
        u32 vu = *(const u32*)(srow + 256);
        float k0 = fmaf(av2, we0, bf2f((u16)(ku & 0xffff)));
        float k1 = fmaf(av2, we1, bf2f((u16)(ku >> 16)));
        float p = fmaf(q0, k0, q1 * k1);
        p += __shfl_xor(p, 1); p += __shfl_xor(p, 2);
        p += __shfl_xor(p, 4); p += __shfl_xor(p, 8);
        float mn = fmaxf(mi, p);
        float fs = __expf(mi - mn);       // exp(-inf)=0 on first edge
        float pe = __expf(p - mn);
        float v0 = fmaf(av2, we0, bf2f((u16)(vu & 0xffff)));
        float v1 = fmaf(av2, we1, bf2f((u16)(vu >> 16)));
        si = fmaf(si, fs, pe);
        a0 = fmaf(a0, fs, pe * v0);
        a1 = fmaf(a1, fs, pe * v1);
        mi = mn;
    }
    float inv = 1.f / (si + 1e-16f);
    u32 su = *(const u32*)&qkvs[(size_t)dstn * 512 + 384 + f0];
    float o0 = fmaxf(fmaf(a0, inv, bf2f((u16)(su & 0xffff))), 0.f);
    float o1 = fmaxf(fmaf(a1, inv, bf2f((u16)(su >> 16))), 0.f);
    float2 o; o.x = o0; o.y = o1;
    *(float2*)&hout[(size_t)dstn * 128 + f0] = o;
}

// ---------------- global mean pool ----------------
__global__ __launch_bounds__(256) void k_pool(
    const float* __restrict__ h, const int* __restrict__ batch,
    float* __restrict__ gsum, float* __restrict__ gcnt)
{
    __shared__ float ssum[8 * 128];
    __shared__ float scnt[8];
    int t = threadIdx.x;
    for (int i = t; i < 8 * 128; i += 256) ssum[i] = 0.f;
    if (t < 8) scnt[t] = 0.f;
    __syncthreads();
    int f = t & 127, half = t >> 7;
    int per = (N_NODES + gridDim.x - 1) / gridDim.x;
    int lo = blockIdx.x * per;
    int hi = lo + per; if (hi > N_NODES) hi = N_NODES;
    float racc = 0.f; float rcnt = 0.f; int rg = -1;
    for (int n = lo + half; n < hi; n += 2) {
        int g = batch[n];
        if (g != rg) {
            if (rg >= 0) { atomicAdd(&ssum[rg * 128 + f], racc); if (f == 0) atomicAdd(&scnt[rg], rcnt); }
            rg = g; racc = 0.f; rcnt = 0.f;
        }
        racc += h[(size_t)n * 128 + f];
        rcnt += 1.f;
    }
    if (rg >= 0) { atomicAdd(&ssum[rg * 128 + f], racc); if (f == 0) atomicAdd(&scnt[rg], rcnt); }
    __syncthreads();
    for (int i = t; i < 8 * 128; i += 256) unsafeAtomicAdd(&gsum[i], ssum[i]);
    if (t < 8) unsafeAtomicAdd(&gcnt[t], scnt[t]);
}

__global__ void k_out(const float* __restrict__ gsum, const float* __restrict__ gcnt,
                      void* __restrict__ outp, const int* __restrict__ flag) {
    int fl = getflag(flag);
    int t = threadIdx.x;  // 1024
    float c = fmaxf(gcnt[t >> 7], 1.f);
    float v = gsum[t] / c;
    if (fl) ((float*)outp)[t] = v;
    else ((u16*)outp)[t] = f2bf(v);
}

extern "C" void kernel_launch(void* const* d_in, const int* in_sizes, int n_in,
                              void* d_out, int out_size, void* d_ws, size_t ws_size,
                              hipStream_t stream)
{
    (void)in_sizes; (void)n_in; (void)out_size; (void)ws_size;
    const void* x    = d_in[0];
    const int* ei    = (const int*)d_in[1];
    const void* ea   = d_in[2];
    const int* batch = (const int*)d_in[3];
    const void* w1   = d_in[4];
    const void* b1   = d_in[5];
    const void* lng  = d_in[6];
    const void* lnb  = d_in[7];
    const void* w2   = d_in[8];
    const void* b2   = d_in[9];
    const int* srcp = ei;
    const int* dstp = ei + N_EDGES;

    char* wsb = (char*)d_ws;
    size_t cur = 0;
    auto alloc = [&](size_t sz) -> void* {
        void* p = wsb + cur;
        cur += (sz + 255) & ~(size_t)255;
        return p;
    };
    float* y      = (float*)alloc((size_t)N_NODES * 128 * 4);   // reused as h3
    float* h1     = (float*)alloc((size_t)N_NODES * 128 * 4);
    float* h2     = (float*)alloc((size_t)N_NODES * 128 * 4);
    u16*   qkvs   = (u16*)  alloc((size_t)N_NODES * 512 * 2);
    float* eaf    = (float*)alloc((size_t)N_EDGES * 4);
    u16*   gt     = (u16*)  alloc(128 * 128 * 2);
    u16*   wcat1  = (u16*)  alloc(512 * 128 * 2);
    u16*   wcat2  = (u16*)  alloc(512 * 128 * 2);
    float* csum   = (float*)alloc(128 * 4);
    float* bwp    = (float*)alloc(128 * 4);
    float* bcat1  = (float*)alloc(512 * 4);
    float* bcat2  = (float*)alloc(512 * 4);
    int*   cntdeg = (int*)  alloc((size_t)N_NODES * 4);
    int*   rowst  = (int*)  alloc((size_t)(N_NODES + 1) * 4);
    int*   nxt    = (int*)  alloc((size_t)N_NODES * 4);
    int*   eids   = (int*)  alloc((size_t)N_EDGES * 4);
    float* gsum   = (float*)alloc((8 * 128 + 8) * 4);
    int*   dtflag = (int*)  alloc(256);
    float* h3 = y;

    hipMemsetAsync(cntdeg, 0, (size_t)N_NODES * 4, stream);
    hipMemsetAsync(gsum, 0, (8 * 128 + 8) * 4, stream);

    k_detect<<<1, 256, 0, stream>>>((const u16*)x, dtflag);
    k_canon_ea<<<3125, 256, 0, stream>>>(ea, eaf, dtflag);

    P8 pw; P8 pb;
    pw.s[0] = d_in[10]; pw.s[1] = d_in[12]; pw.s[2] = d_in[14]; pw.s[3] = d_in[17];
    pw.s[4] = d_in[19]; pw.s[5] = d_in[21]; pw.s[6] = d_in[23]; pw.s[7] = d_in[26];
    pb.s[0] = d_in[11]; pb.s[1] = d_in[13]; pb.s[2] = d_in[15]; pb.s[3] = d_in[18];
    pb.s[4] = d_in[20]; pb.s[5] = d_in[22]; pb.s[6] = d_in[24]; pb.s[7] = d_in[27];
    k_transpose8<<<512, 256, 0, stream>>>(pw, wcat1, wcat2, dtflag);
    k_bcat8<<<4, 256, 0, stream>>>(pb, bcat1, bcat2, dtflag);
    k_prep_w2<<<1, 128, 0, stream>>>(w2, lng, lnb, b2, gt, csum, bwp, dtflag);

    k_embed_lin1<<<782, 256, 0, stream>>>(x, w1, b1, y, dtflag);
    k_degree<<<3125, 256, 0, stream>>>(dstp, cntdeg);
    k_scan<<<1, 1024, 0, stream>>>(cntdeg, rowst, nxt);
    k_scatter<<<3125, 256, 0, stream>>>(dstp, nxt, eids);
    k_embed_edges<<<12500, 256, 0, stream>>>(y, srcp, eaf, rowst, eids,
                                             w1, lng, lnb, gt, csum, bwp, h1, dtflag);
    k_proj<<<782, 256, 0, stream>>>(h1, wcat1, bcat1, qkvs);
    k_attn<<<12500, 256, 0, stream>>>(qkvs, rowst, eids, srcp, eaf, d_in[16], h2, dtflag);
    k_proj<<<782, 256, 0, stream>>>(h2, wcat2, bcat2, qkvs);
    k_attn<<<12500, 256, 0, stream>>>(qkvs, rowst, eids, srcp, eaf, d_in[25], h3, dtflag);
    k_pool<<<128, 256, 0, stream>>>(h3, batch, gsum, gsum + 8 * 128);
    k_out<<<1, 1024, 0, stream>>>(gsum, gsum + 8 * 128, d_out, dtflag);
}

// Round 4
// 1053.744 us; speedup vs baseline: 1.5251x; 1.5251x over previous
//
#include <hip/hip_runtime.h>

typedef unsigned short u16;
typedef unsigned int u32;
typedef __attribute__((ext_vector_type(8))) short bf16x8;
typedef __attribute__((ext_vector_type(4))) float f32x4;

#define N_NODES 50000
#define N_EDGES 800000

__device__ __forceinline__ float bf2f(u16 u) {
    union { u32 i; float f; } v; v.i = ((u32)u) << 16; return v.f;
}
__device__ __forceinline__ u16 f2bf(float f) {
    union { u32 i; float f; } v; v.f = f;
    u32 i = v.i;
    return (u16)((i + 0x7FFFu + ((i >> 16) & 1u)) >> 16);
}
// dtype-agnostic load: fl!=0 -> float32 buffer, else bf16 (u16) buffer
__device__ __forceinline__ float ldf(const void* p, int i, int fl) {
    return fl ? ((const float*)p)[i] : bf2f(((const u16*)p)[i]);
}
__device__ __forceinline__ int getflag(const int* flag) {
    return __builtin_amdgcn_readfirstlane(*flag);
}

// ---------------- dtype detection ----------------
__global__ void k_detect(const u16* __restrict__ xr, int* __restrict__ flag) {
    __shared__ int sc[256];
    int t = threadIdx.x;
    int c = 0;
    for (int i = t; i < 4096; i += 256) {
        u32 e = (xr[i] >> 7) & 0xFF;
        if (e >= 143) c++;
    }
    sc[t] = c;
    __syncthreads();
    for (int s = 128; s > 0; s >>= 1) {
        if (t < s) sc[t] += sc[t + s];
        __syncthreads();
    }
    if (t == 0) *flag = (sc[0] > 64) ? 1 : 0;   // 1 = float32, 0 = bf16
}

__global__ void k_canon_ea(const void* __restrict__ ea, float* __restrict__ eaf,
                           const int* __restrict__ flag) {
    int fl = getflag(flag);
    int e = blockIdx.x * 256 + threadIdx.x;
    if (e < N_EDGES) eaf[e] = ldf(ea, e, fl);
}

// ---------------- weight prep ----------------
struct P8 { const void* s[8]; };

__global__ void k_transpose8(P8 p, u16* __restrict__ dst0, u16* __restrict__ dst1,
                             const int* __restrict__ flag) {
    int fl = getflag(flag);
    int gid = blockIdx.x * 256 + threadIdx.x;   // 512 blocks -> 8 * 16384
    int wi = gid >> 14;
    int id = gid & 16383;
    int k = id >> 7, n = id & 127;
    u16* d = (wi < 4) ? (dst0 + wi * 16384) : (dst1 + (wi - 4) * 16384);
    d[n * 128 + k] = f2bf(ldf(p.s[wi], id, fl));
}

__global__ void k_bcat8(P8 p, float* __restrict__ out1, float* __restrict__ out2,
                        const int* __restrict__ flag) {
    int fl = getflag(flag);
    int t = blockIdx.x * 256 + threadIdx.x;   // 4 blocks -> 1024
    float v = ldf(p.s[t >> 7], t & 127, fl);
    if (t < 512) out1[t] = v; else out2[t - 512] = v;
}

// G = diag(lng)*W2 folded; csum[n] = sum_f G[f,n]; bwp[n] = sum_f lnb_f*W2[f,n] + b2[n]
__global__ void k_prep_w2(const void* __restrict__ w2, const void* __restrict__ lng_,
                          const void* __restrict__ lnb_, const void* __restrict__ b2_,
                          u16* __restrict__ gt, float* __restrict__ csum,
                          float* __restrict__ bwp, const int* __restrict__ flag)
{
    int fl = getflag(flag);
    int t = threadIdx.x;   // 128 threads, 1 block; t = output column n
    if (t < 128) {
        float cs = 0.f, bw = 0.f;
        for (int f = 0; f < 128; f++) {
            float wv = ldf(w2, f * 128 + t, fl);
            float g = ldf(lng_, f, fl);
            float b = ldf(lnb_, f, fl);
            u16 gwq = f2bf(g * wv);
            gt[t * 128 + f] = gwq;
            cs += bf2f(gwq);
            bw = fmaf(b, wv, bw);
        }
        csum[t] = cs;
        bwp[t] = bw + ldf(b2_, t, fl);
    }
}

// ---------------- embed: node-side lin1  y = x @ W1[:64] + b1 ----------------
__global__ __launch_bounds__(256) void k_embed_lin1(
    const void* __restrict__ x, const void* __restrict__ w1,
    const void* __restrict__ b1, float* __restrict__ y,
    const int* __restrict__ flag)
{
    __shared__ float sx[2][64];
    int fl = getflag(flag);
    int t = threadIdx.x;
    int col = t & 127, half = t >> 7;
    float wreg[64];
    #pragma unroll
    for (int k = 0; k < 64; k++) wreg[k] = ldf(w1, k * 128 + col, fl);
    float bias = ldf(b1, col, fl);
    int base = blockIdx.x * 64;
    for (int it = 0; it < 32; ++it) {
        __syncthreads();
        if (t < 128) {
            int nh = base + it * 2 + (t >> 6);
            sx[t >> 6][t & 63] = (nh < N_NODES) ? ldf(x, nh * 64 + (t & 63), fl) : 0.f;
        }
        __syncthreads();
        float acc = bias;
        #pragma unroll
        for (int k = 0; k < 64; k++) acc = fmaf(sx[half][k], wreg[k], acc);
        int n = base + it * 2 + half;
        if (n < N_NODES) y[(size_t)n * 128 + col] = acc;
    }
}

// ---------------- CSR build ----------------
__global__ void k_degree(const int* __restrict__ dst, int* __restrict__ cnt) {
    int e = blockIdx.x * 256 + threadIdx.x;
    if (e < N_EDGES) atomicAdd(&cnt[dst[e]], 1);
}

__global__ __launch_bounds__(1024) void k_scan(const int* __restrict__ cnt,
                                               int* __restrict__ row_start,
                                               int* __restrict__ nxt)
{
    __shared__ int wsum[16];
    __shared__ int s_tot;
    int t = threadIdx.x, lane = t & 63, wid = t >> 6;
    int run = 0;
    for (int base = 0; base < N_NODES; base += 8192) {
        int i0 = base + t * 8;
        int v[8], pre[8];
        int s = 0;
        #pragma unroll
        for (int j = 0; j < 8; j++) {
            int i = i0 + j;
            v[j] = (i < N_NODES) ? cnt[i] : 0;
            pre[j] = s;
            s += v[j];
        }
        int tsum = s;
        int sc = tsum;
        #pragma unroll
        for (int off = 1; off < 64; off <<= 1) {
            int o = __shfl_up(sc, off);
            if (lane >= off) sc += o;
        }
        if (lane == 63) wsum[wid] = sc;
        __syncthreads();
        if (t == 0) {
            int acc2 = 0;
            #pragma unroll
            for (int k2 = 0; k2 < 16; k2++) { int vv = wsum[k2]; wsum[k2] = acc2; acc2 += vv; }
            s_tot = acc2;
        }
        __syncthreads();
        int texcl = run + wsum[wid] + (sc - tsum);
        #pragma unroll
        for (int j = 0; j < 8; j++) {
            int i = i0 + j;
            if (i < N_NODES) { int ex = texcl + pre[j]; row_start[i] = ex; nxt[i] = ex; }
        }
        run += s_tot;
        __syncthreads();
    }
    if (t == 0) row_start[N_NODES] = run;
}

__global__ void k_scatter(const int* __restrict__ dst, int* __restrict__ nxt,
                          int* __restrict__ eids) {
    int e = blockIdx.x * 256 + threadIdx.x;
    if (e < N_EDGES) { int p = atomicAdd(&nxt[dst[e]], 1); eids[p] = e; }
}

// ---------------- embed: persistent wave-per-node per-edge MLP, register aggregation ----------------
// LN1 affine folded into B (G = diag(g)W2): C = rs*(A_relu@G - mu*csum) + bwp
// LN2 affine folded out of aggregation: h = g*(sum rs2*z - sum rs2*mu2) + deg*b
// NOTE: no forced min-occupancy — R3's __launch_bounds__(256,4) capped VGPR at 64 and
// spilled ~500B/thread to scratch (WRITE_SIZE 1.7GB). Let VGPR float.
__global__ __launch_bounds__(256) void k_embed_edges(
    const float* __restrict__ y,
    const int* __restrict__ srcp, const float* __restrict__ eaf,
    const int* __restrict__ rowst, const int* __restrict__ eids,
    const void* __restrict__ w1, const void* __restrict__ lng, const void* __restrict__ lnb,
    const u16* __restrict__ gt, const float* __restrict__ csum, const float* __restrict__ bwp,
    float* __restrict__ h1, const int* __restrict__ flag)
{
    __shared__ u16 sB[128 * 136];   // G^T, padded rows (2-way bank conflict = free)
    int fl = getflag(flag);
    int t = threadIdx.x;
    for (int c = t; c < 128 * 32; c += 256) {
        int row = c >> 5, ch = c & 31;
        *(ushort4*)&sB[row * 136 + ch * 4] = *(const ushort4*)&gt[row * 128 + ch * 4];
    }
    int l = t & 63, w = t >> 6;
    int m = l & 15, q = l >> 4;

    // packed-bf16 W1 edge row, features f = kb*32 + q*8 + j
    u32 w1p[4][4];
    #pragma unroll
    for (int kb = 0; kb < 4; kb++)
        #pragma unroll
        for (int jj = 0; jj < 4; jj++) {
            int f = kb * 32 + q * 8 + jj * 2;
            w1p[kb][jj] = (u32)f2bf(ldf(w1, 64 * 128 + f, fl)) |
                          ((u32)f2bf(ldf(w1, 64 * 128 + f + 1, fl)) << 16);
        }
    float csum_r[8], bwp_r[8];
    #pragma unroll
    for (int nb = 0; nb < 8; nb++) {
        csum_r[nb] = csum[nb * 16 + m];
        bwp_r[nb]  = bwp[nb * 16 + m];
    }
    float g2c[8], b2n[8];
    #pragma unroll
    for (int nb = 0; nb < 8; nb++) {
        g2c[nb] = ldf(lng, nb * 16 + m, fl);
        b2n[nb] = ldf(lnb, nb * 16 + m, fl);
    }
    __syncthreads();

    f32x4 zf = {0.f, 0.f, 0.f, 0.f};
    int stride = gridDim.x * 4;
    for (int node = blockIdx.x * 4 + w; node < N_NODES; node += stride) {
        int rs = rowst[node], re = rowst[node + 1];
        float hacc[8];
        #pragma unroll
        for (int nb = 0; nb < 8; nb++) hacc[nb] = 0.f;
        float V = 0.f;

        for (int base = rs; base < re; base += 16) {
            int idx = base + m;
            int eidx = (idx < re) ? idx : (re - 1);
            int eid = eids[eidx];
            int srcn = srcp[eid];
            float av = eaf[eid];

            const float* yrow = y + (size_t)srcn * 128 + q * 8;
            bf16x8 afrag[4];
            float s1 = 0.f, s2 = 0.f;
            #pragma unroll
            for (int kb = 0; kb < 4; kb++) {
                const float4* p = (const float4*)(yrow + kb * 32);
                float4 u0 = p[0], u1 = p[1];
                float tv[8] = {u0.x, u0.y, u0.z, u0.w, u1.x, u1.y, u1.z, u1.w};
                #pragma unroll
                for (int j = 0; j < 8; j++) {
                    float wv = bf2f((u16)((w1p[kb][j >> 1] >> ((j & 1) * 16)) & 0xffff));
                    float vv = fmaxf(fmaf(av, wv, tv[j]), 0.f);
                    s1 += vv; s2 = fmaf(vv, vv, s2);
                    afrag[kb][j] = (short)f2bf(vv);
                }
            }
            s1 += __shfl_xor(s1, 16); s2 += __shfl_xor(s2, 16);
            s1 += __shfl_xor(s1, 32); s2 += __shfl_xor(s2, 32);
            float mu = s1 * (1.f / 128.f);
            float rsd = rsqrtf(s2 * (1.f / 128.f) - mu * mu + 1e-5f);

            f32x4 acc[8];
            #pragma unroll
            for (int nb = 0; nb < 8; nb++) acc[nb] = zf;
            #pragma unroll
            for (int nb = 0; nb < 8; nb++) {
                const u16* brow = &sB[(nb * 16 + m) * 136 + q * 8];
                #pragma unroll
                for (int kb = 0; kb < 4; kb++) {
                    bf16x8 bfrag = *(const bf16x8*)(brow + kb * 32);
                    acc[nb] = __builtin_amdgcn_mfma_f32_16x16x32_bf16(afrag[kb], bfrag, acc[nb], 0, 0, 0);
                }
            }
            // per-edge epilogue: C -> relu -> LN2 stats -> masked accumulate
            #pragma unroll
            for (int r = 0; r < 4; r++) {
                int e = q * 4 + r;
                float murow = __shfl(mu, e);
                float rsrow = __shfl(rsd, e);
                float z[8]; float t1 = 0.f, t2 = 0.f;
                #pragma unroll
                for (int nb = 0; nb < 8; nb++) {
                    float cval = fmaf(rsrow, fmaf(-murow, csum_r[nb], acc[nb][r]), bwp_r[nb]);
                    float zz = fmaxf(cval, 0.f);
                    z[nb] = zz; t1 += zz; t2 = fmaf(zz, zz, t2);
                }
                #pragma unroll
                for (int o = 1; o < 16; o <<= 1) { t1 += __shfl_xor(t1, o); t2 += __shfl_xor(t2, o); }
                float mu2 = t1 * (1.f / 128.f);
                float rs2 = rsqrtf(t2 * (1.f / 128.f) - mu2 * mu2 + 1e-5f);
                if (base + e >= re) rs2 = 0.f;   // mask pad edges
                V = fmaf(mu2, rs2, V);
                #pragma unroll
                for (int nb = 0; nb < 8; nb++) hacc[nb] = fmaf(rs2, z[nb], hacc[nb]);
            }
        }
        // cross-quad reduce and single store
        #pragma unroll
        for (int nb = 0; nb < 8; nb++) {
            hacc[nb] += __shfl_xor(hacc[nb], 16);
            hacc[nb] += __shfl_xor(hacc[nb], 32);
        }
        V += __shfl_xor(V, 16); V += __shfl_xor(V, 32);
        if (q == 0) {
            float dg = (float)(re - rs);
            #pragma unroll
            for (int nb = 0; nb < 8; nb++) {
                int f2 = nb * 16 + m;
                h1[(size_t)node * 128 + f2] = fmaf(g2c[nb], hacc[nb] - V, dg * b2n[nb]);
            }
        }
    }
}

// ---------------- fused q/k/v/skip projection GEMM ----------------
__global__ __launch_bounds__(256) void k_proj(
    const float* __restrict__ hin, const u16* __restrict__ wt,
    const float* __restrict__ bcat, u16* __restrict__ outp)
{
    __shared__ u16 sA[64 * 136];
    __shared__ u16 sB[128 * 136];
    int t = threadIdx.x;
    int l = t & 63, w = t >> 6;
    int m = l & 15, q = l >> 4;
    int rowbase = blockIdx.x * 64;
    for (int c = t; c < 64 * 32; c += 256) {
        int row = c >> 5, ch = c & 31;
        int gr = rowbase + row;
        float4 v;
        if (gr < N_NODES) v = *(const float4*)&hin[(size_t)gr * 128 + ch * 4];
        else v = make_float4(0.f, 0.f, 0.f, 0.f);
        ushort4 pk;
        pk.x = f2bf(v.x); pk.y = f2bf(v.y); pk.z = f2bf(v.z); pk.w = f2bf(v.w);
        *(ushort4*)&sA[row * 136 + ch * 4] = pk;
    }
    __syncthreads();
    bf16x8 afrag[4];
    #pragma unroll
    for (int kb = 0; kb < 4; kb++)
        afrag[kb] = *(const bf16x8*)&sA[(w * 16 + m) * 136 + kb * 32 + q * 8];

    f32x4 zf = {0.f, 0.f, 0.f, 0.f};
    for (int g = 0; g < 4; ++g) {
        __syncthreads();
        for (int c = t; c < 128 * 32; c += 256) {
            int row = c >> 5, ch = c & 31;
            *(ushort4*)&sB[row * 136 + ch * 4] = *(const ushort4*)&wt[(g * 128 + row) * 128 + ch * 4];
        }
        __syncthreads();
        f32x4 acc[8];
        #pragma unroll
        for (int nb = 0; nb < 8; nb++) acc[nb] = zf;
        #pragma unroll
        for (int nb = 0; nb < 8; nb++) {
            const u16* brow = &sB[(nb * 16 + m) * 136 + q * 8];
            #pragma unroll
            for (int kb = 0; kb < 4; kb++) {
                bf16x8 bfrag = *(const bf16x8*)(brow + kb * 32);
                acc[nb] = __builtin_amdgcn_mfma_f32_16x16x32_bf16(afrag[kb], bfrag, acc[nb], 0, 0, 0);
            }
        }
        #pragma unroll
        for (int nb = 0; nb < 8; nb++) {
            int col = g * 128 + nb * 16 + m;
            float bb = bcat[col];
            #pragma unroll
            for (int r = 0; r < 4; r++) {
                int row = rowbase + w * 16 + q * 4 + r;
                if (row < N_NODES) outp[(size_t)row * 512 + col] = f2bf(acc[nb][r] + bb);
            }
        }
    }
}

// ---------------- attention: wave per dst node, online softmax over in-edges ----------------
__global__ __launch_bounds__(256) void k_attn(
    const u16* __restrict__ qkvs,
    const int* __restrict__ rowst, const int* __restrict__ eids,
    const int* __restrict__ srcp, const float* __restrict__ eaf,
    const void* __restrict__ wep, float* __restrict__ hout,
    const int* __restrict__ flag)
{
    int fl = getflag(flag);
    int t = threadIdx.x;
    int l = t & 63, w = t >> 6;
    int dstn = blockIdx.x * 4 + w;        // grid*4 == N exactly
    int f0 = l * 2;                       // features 2l, 2l+1; head = l>>4
    u32 qu = *(const u32*)&qkvs[(size_t)dstn * 512 + f0];
    const float scale = 0.17677669529663687f;  // 1/sqrt(32)
    float q0 = bf2f((u16)(qu & 0xffff)) * scale;
    float q1 = bf2f((u16)(qu >> 16)) * scale;
    float we0 = ldf(wep, f0, fl);
    float we1 = ldf(wep, f0 + 1, fl);
    float mi = -INFINITY, si = 0.f, a0 = 0.f, a1 = 0.f;
    int rs = rowst[dstn], re = rowst[dstn + 1];
    // 1-stage software pipeline on the index chain
    int sn = 0; float av = 0.f;
    if (rs < re) { int e0 = eids[rs]; sn = srcp[e0]; av = eaf[e0]; }
    for (int i = rs; i < re; ++i) {
        int sn2 = sn; float av2 = av;
        if (i + 1 < re) { int e1 = eids[i + 1]; sn = srcp[e1]; av = eaf[e1]; }
        const u16* srow = &qkvs[(size_t)sn2 * 512 + f0];
        u32 ku = *(const u32*)(srow + 128);
        u32 vu = *(const u32*)(srow + 256);
        float k0 = fmaf(av2, we0, bf2f((u16)(ku & 0xffff)));
        float k1 = fmaf(av2, we1, bf2f((u16)(ku >> 16)));
        float p = fmaf(q0, k0, q1 * k1);
        p += __shfl_xor(p, 1); p += __shfl_xor(p, 2);
        p += __shfl_xor(p, 4); p += __shfl_xor(p, 8);
        float mn = fmaxf(mi, p);
        float fs = __expf(mi - mn);       // exp(-inf)=0 on first edge
        float pe = __expf(p - mn);
        float v0 = fmaf(av2, we0, bf2f((u16)(vu & 0xffff)));
        float v1 = fmaf(av2, we1, bf2f((u16)(vu >> 16)));
        si = fmaf(si, fs, pe);
        a0 = fmaf(a0, fs, pe * v0);
        a1 = fmaf(a1, fs, pe * v1);
        mi = mn;
    }
    float inv = 1.f / (si + 1e-16f);
    u32 su = *(const u32*)&qkvs[(size_t)dstn * 512 + 384 + f0];
    float o0 = fmaxf(fmaf(a0, inv, bf2f((u16)(su & 0xffff))), 0.f);
    float o1 = fmaxf(fmaf(a1, inv, bf2f((u16)(su >> 16))), 0.f);
    float2 o; o.x = o0; o.y = o1;
    *(float2*)&hout[(size_t)dstn * 128 + f0] = o;
}

// ---------------- global mean pool ----------------
__global__ __launch_bounds__(256) void k_pool(
    const float* __restrict__ h, const int* __restrict__ batch,
    float* __restrict__ gsum, float* __restrict__ gcnt)
{
    __shared__ float ssum[8 * 128];
    __shared__ float scnt[8];
    int t = threadIdx.x;
    for (int i = t; i < 8 * 128; i += 256) ssum[i] = 0.f;
    if (t < 8) scnt[t] = 0.f;
    __syncthreads();
    int f = t & 127, half = t >> 7;
    int per = (N_NODES + gridDim.x - 1) / gridDim.x;
    int lo = blockIdx.x * per;
    int hi = lo + per; if (hi > N_NODES) hi = N_NODES;
    float racc = 0.f; float rcnt = 0.f; int rg = -1;
    for (int n = lo + half; n < hi; n += 2) {
        int g = batch[n];
        if (g != rg) {
            if (rg >= 0) { atomicAdd(&ssum[rg * 128 + f], racc); if (f == 0) atomicAdd(&scnt[rg], rcnt); }
            rg = g; racc = 0.f; rcnt = 0.f;
        }
        racc += h[(size_t)n * 128 + f];
        rcnt += 1.f;
    }
    if (rg >= 0) { atomicAdd(&ssum[rg * 128 + f], racc); if (f == 0) atomicAdd(&scnt[rg], rcnt); }
    __syncthreads();
    for (int i = t; i < 8 * 128; i += 256) unsafeAtomicAdd(&gsum[i], ssum[i]);
    if (t < 8) unsafeAtomicAdd(&gcnt[t], scnt[t]);
}

__global__ void k_out(const float* __restrict__ gsum, const float* __restrict__ gcnt,
                      void* __restrict__ outp, const int* __restrict__ flag) {
    int fl = getflag(flag);
    int t = threadIdx.x;  // 1024
    float c = fmaxf(gcnt[t >> 7], 1.f);
    float v = gsum[t] / c;
    if (fl) ((float*)outp)[t] = v;
    else ((u16*)outp)[t] = f2bf(v);
}

extern "C" void kernel_launch(void* const* d_in, const int* in_sizes, int n_in,
                              void* d_out, int out_size, void* d_ws, size_t ws_size,
                              hipStream_t stream)
{
    (void)in_sizes; (void)n_in; (void)out_size; (void)ws_size;
    const void* x    = d_in[0];
    const int* ei    = (const int*)d_in[1];
    const void* ea   = d_in[2];
    const int* batch = (const int*)d_in[3];
    const void* w1   = d_in[4];
    const void* b1   = d_in[5];
    const void* lng  = d_in[6];
    const void* lnb  = d_in[7];
    const void* w2   = d_in[8];
    const void* b2   = d_in[9];
    const int* srcp = ei;
    const int* dstp = ei + N_EDGES;

    char* wsb = (char*)d_ws;
    size_t cur = 0;
    auto alloc = [&](size_t sz) -> void* {
        void* p = wsb + cur;
        cur += (sz + 255) & ~(size_t)255;
        return p;
    };
    float* y      = (float*)alloc((size_t)N_NODES * 128 * 4);   // reused as h3
    float* h1     = (float*)alloc((size_t)N_NODES * 128 * 4);
    float* h2     = (float*)alloc((size_t)N_NODES * 128 * 4);
    u16*   qkvs   = (u16*)  alloc((size_t)N_NODES * 512 * 2);
    float* eaf    = (float*)alloc((size_t)N_EDGES * 4);
    u16*   gt     = (u16*)  alloc(128 * 128 * 2);
    u16*   wcat1  = (u16*)  alloc(512 * 128 * 2);
    u16*   wcat2  = (u16*)  alloc(512 * 128 * 2);
    float* csum   = (float*)alloc(128 * 4);
    float* bwp    = (float*)alloc(128 * 4);
    float* bcat1  = (float*)alloc(512 * 4);
    float* bcat2  = (float*)alloc(512 * 4);
    int*   cntdeg = (int*)  alloc((size_t)N_NODES * 4);
    int*   rowst  = (int*)  alloc((size_t)(N_NODES + 1) * 4);
    int*   nxt    = (int*)  alloc((size_t)N_NODES * 4);
    int*   eids   = (int*)  alloc((size_t)N_EDGES * 4);
    float* gsum   = (float*)alloc((8 * 128 + 8) * 4);
    int*   dtflag = (int*)  alloc(256);
    float* h3 = y;

    hipMemsetAsync(cntdeg, 0, (size_t)N_NODES * 4, stream);
    hipMemsetAsync(gsum, 0, (8 * 128 + 8) * 4, stream);

    k_detect<<<1, 256, 0, stream>>>((const u16*)x, dtflag);
    k_canon_ea<<<3125, 256, 0, stream>>>(ea, eaf, dtflag);

    P8 pw; P8 pb;
    pw.s[0] = d_in[10]; pw.s[1] = d_in[12]; pw.s[2] = d_in[14]; pw.s[3] = d_in[17];
    pw.s[4] = d_in[19]; pw.s[5] = d_in[21]; pw.s[6] = d_in[23]; pw.s[7] = d_in[26];
    pb.s[0] = d_in[11]; pb.s[1] = d_in[13]; pb.s[2] = d_in[15]; pb.s[3] = d_in[18];
    pb.s[4] = d_in[20]; pb.s[5] = d_in[22]; pb.s[6] = d_in[24]; pb.s[7] = d_in[27];
    k_transpose8<<<512, 256, 0, stream>>>(pw, wcat1, wcat2, dtflag);
    k_bcat8<<<4, 256, 0, stream>>>(pb, bcat1, bcat2, dtflag);
    k_prep_w2<<<1, 128, 0, stream>>>(w2, lng, lnb, b2, gt, csum, bwp, dtflag);

    k_embed_lin1<<<782, 256, 0, stream>>>(x, w1, b1, y, dtflag);
    k_degree<<<3125, 256, 0, stream>>>(dstp, cntdeg);
    k_scan<<<1, 1024, 0, stream>>>(cntdeg, rowst, nxt);
    k_scatter<<<3125, 256, 0, stream>>>(dstp, nxt, eids);
    k_embed_edges<<<2048, 256, 0, stream>>>(y, srcp, eaf, rowst, eids,
                                            w1, lng, lnb, gt, csum, bwp, h1, dtflag);
    k_proj<<<782, 256, 0, stream>>>(h1, wcat1, bcat1, qkvs);
    k_attn<<<12500, 256, 0, stream>>>(qkvs, rowst, eids, srcp, eaf, d_in[16], h2, dtflag);
    k_proj<<<782, 256, 0, stream>>>(h2, wcat2, bcat2, qkvs);
    k_attn<<<12500, 256, 0, stream>>>(qkvs, rowst, eids, srcp, eaf, d_in[25], h3, dtflag);
    k_pool<<<128, 256, 0, stream>>>(h3, batch, gsum, gsum + 8 * 128);
    k_out<<<1, 1024, 0, stream>>>(gsum, gsum + 8 * 128, d_out, dtflag);
}

// Round 5
// 1006.062 us; speedup vs baseline: 1.5974x; 1.0474x over previous
//
#include <hip/hip_runtime.h>

typedef unsigned short u16;
typedef unsigned int u32;
typedef __attribute__((ext_vector_type(8))) short bf16x8;
typedef __attribute__((ext_vector_type(4))) float f32x4;

#define N_NODES 50000
#define N_EDGES 800000

__device__ __forceinline__ float bf2f(u16 u) {
    union { u32 i; float f; } v; v.i = ((u32)u) << 16; return v.f;
}
__device__ __forceinline__ u16 f2bf(float f) {
    union { u32 i; float f; } v; v.f = f;
    u32 i = v.i;
    return (u16)((i + 0x7FFFu + ((i >> 16) & 1u)) >> 16);
}
// dtype-agnostic load: fl!=0 -> float32 buffer, else bf16 (u16) buffer
__device__ __forceinline__ float ldf(const void* p, int i, int fl) {
    return fl ? ((const float*)p)[i] : bf2f(((const u16*)p)[i]);
}
__device__ __forceinline__ int getflag(const int* flag) {
    return __builtin_amdgcn_readfirstlane(*flag);
}

// ---------------- dtype detection ----------------
__global__ void k_detect(const u16* __restrict__ xr, int* __restrict__ flag) {
    __shared__ int sc[256];
    int t = threadIdx.x;
    int c = 0;
    for (int i = t; i < 4096; i += 256) {
        u32 e = (xr[i] >> 7) & 0xFF;
        if (e >= 143) c++;
    }
    sc[t] = c;
    __syncthreads();
    for (int s = 128; s > 0; s >>= 1) {
        if (t < s) sc[t] += sc[t + s];
        __syncthreads();
    }
    if (t == 0) *flag = (sc[0] > 64) ? 1 : 0;   // 1 = float32, 0 = bf16
}

__global__ void k_canon_ea(const void* __restrict__ ea, float* __restrict__ eaf,
                           const int* __restrict__ flag) {
    int fl = getflag(flag);
    int e = blockIdx.x * 256 + threadIdx.x;
    if (e < N_EDGES) eaf[e] = ldf(ea, e, fl);
}

// ---------------- weight prep ----------------
struct P8 { const void* s[8]; };

__global__ void k_transpose8(P8 p, u16* __restrict__ dst0, u16* __restrict__ dst1,
                             const int* __restrict__ flag) {
    int fl = getflag(flag);
    int gid = blockIdx.x * 256 + threadIdx.x;   // 512 blocks -> 8 * 16384
    int wi = gid >> 14;
    int id = gid & 16383;
    int k = id >> 7, n = id & 127;
    u16* d = (wi < 4) ? (dst0 + wi * 16384) : (dst1 + (wi - 4) * 16384);
    d[n * 128 + k] = f2bf(ldf(p.s[wi], id, fl));
}

__global__ void k_bcat8(P8 p, float* __restrict__ out1, float* __restrict__ out2,
                        const int* __restrict__ flag) {
    int fl = getflag(flag);
    int t = blockIdx.x * 256 + threadIdx.x;   // 4 blocks -> 1024
    float v = ldf(p.s[t >> 7], t & 127, fl);
    if (t < 512) out1[t] = v; else out2[t - 512] = v;
}

// G = diag(lng)*W2 folded; csum[n] = sum_f G[f,n]; bwp[n] = sum_f lnb_f*W2[f,n] + b2[n]
__global__ void k_prep_w2(const void* __restrict__ w2, const void* __restrict__ lng_,
                          const void* __restrict__ lnb_, const void* __restrict__ b2_,
                          u16* __restrict__ gt, float* __restrict__ csum,
                          float* __restrict__ bwp, const int* __restrict__ flag)
{
    int fl = getflag(flag);
    int t = threadIdx.x;   // 128 threads, 1 block; t = output column n
    if (t < 128) {
        float cs = 0.f, bw = 0.f;
        for (int f = 0; f < 128; f++) {
            float wv = ldf(w2, f * 128 + t, fl);
            float g = ldf(lng_, f, fl);
            float b = ldf(lnb_, f, fl);
            u16 gwq = f2bf(g * wv);
            gt[t * 128 + f] = gwq;
            cs += bf2f(gwq);
            bw = fmaf(b, wv, bw);
        }
        csum[t] = cs;
        bwp[t] = bw + ldf(b2_, t, fl);
    }
}

// ---------------- embed: node-side lin1  y = x @ W1[:64] + b1  (bf16 out) ----------------
__global__ __launch_bounds__(256) void k_embed_lin1(
    const void* __restrict__ x, const void* __restrict__ w1,
    const void* __restrict__ b1, u16* __restrict__ y,
    const int* __restrict__ flag)
{
    __shared__ float sx[2][64];
    int fl = getflag(flag);
    int t = threadIdx.x;
    int col = t & 127, half = t >> 7;
    float wreg[64];
    #pragma unroll
    for (int k = 0; k < 64; k++) wreg[k] = ldf(w1, k * 128 + col, fl);
    float bias = ldf(b1, col, fl);
    int base = blockIdx.x * 64;
    for (int it = 0; it < 32; ++it) {
        __syncthreads();
        if (t < 128) {
            int nh = base + it * 2 + (t >> 6);
            sx[t >> 6][t & 63] = (nh < N_NODES) ? ldf(x, nh * 64 + (t & 63), fl) : 0.f;
        }
        __syncthreads();
        float acc = bias;
        #pragma unroll
        for (int k = 0; k < 64; k++) acc = fmaf(sx[half][k], wreg[k], acc);
        int n = base + it * 2 + half;
        if (n < N_NODES) y[(size_t)n * 128 + col] = f2bf(acc);
    }
}

// ---------------- CSR build ----------------
__global__ void k_degree(const int* __restrict__ dst, int* __restrict__ cnt) {
    int e = blockIdx.x * 256 + threadIdx.x;
    if (e < N_EDGES) atomicAdd(&cnt[dst[e]], 1);
}

__global__ __launch_bounds__(1024) void k_scan(const int* __restrict__ cnt,
                                               int* __restrict__ row_start,
                                               int* __restrict__ nxt)
{
    __shared__ int wsum[16];
    __shared__ int s_tot;
    int t = threadIdx.x, lane = t & 63, wid = t >> 6;
    int run = 0;
    for (int base = 0; base < N_NODES; base += 8192) {
        int i0 = base + t * 8;
        int v[8], pre[8];
        int s = 0;
        #pragma unroll
        for (int j = 0; j < 8; j++) {
            int i = i0 + j;
            v[j] = (i < N_NODES) ? cnt[i] : 0;
            pre[j] = s;
            s += v[j];
        }
        int tsum = s;
        int sc = tsum;
        #pragma unroll
        for (int off = 1; off < 64; off <<= 1) {
            int o = __shfl_up(sc, off);
            if (lane >= off) sc += o;
        }
        if (lane == 63) wsum[wid] = sc;
        __syncthreads();
        if (t == 0) {
            int acc2 = 0;
            #pragma unroll
            for (int k2 = 0; k2 < 16; k2++) { int vv = wsum[k2]; wsum[k2] = acc2; acc2 += vv; }
            s_tot = acc2;
        }
        __syncthreads();
        int texcl = run + wsum[wid] + (sc - tsum);
        #pragma unroll
        for (int j = 0; j < 8; j++) {
            int i = i0 + j;
            if (i < N_NODES) { int ex = texcl + pre[j]; row_start[i] = ex; nxt[i] = ex; }
        }
        run += s_tot;
        __syncthreads();
    }
    if (t == 0) row_start[N_NODES] = run;
}

__global__ void k_scatter(const int* __restrict__ dst, int* __restrict__ nxt,
                          int* __restrict__ eids) {
    int e = blockIdx.x * 256 + threadIdx.x;
    if (e < N_EDGES) { int p = atomicAdd(&nxt[dst[e]], 1); eids[p] = e; }
}

// ---------------- embed: persistent wave-per-node per-edge MLP, register aggregation ----------------
// y is bf16 (halves gather traffic). LN affines folded as in R3/R4.
__global__ __launch_bounds__(256) void k_embed_edges(
    const u16* __restrict__ y,
    const int* __restrict__ srcp, const float* __restrict__ eaf,
    const int* __restrict__ rowst, const int* __restrict__ eids,
    const void* __restrict__ w1, const void* __restrict__ lng, const void* __restrict__ lnb,
    const u16* __restrict__ gt, const float* __restrict__ csum, const float* __restrict__ bwp,
    float* __restrict__ h1, const int* __restrict__ flag)
{
    __shared__ u16 sB[128 * 136];   // G^T, padded rows (2-way bank conflict = free)
    int fl = getflag(flag);
    int t = threadIdx.x;
    for (int c = t; c < 128 * 32; c += 256) {
        int row = c >> 5, ch = c & 31;
        *(ushort4*)&sB[row * 136 + ch * 4] = *(const ushort4*)&gt[row * 128 + ch * 4];
    }
    int l = t & 63, w = t >> 6;
    int m = l & 15, q = l >> 4;

    // packed-bf16 W1 edge row, features f = kb*32 + q*8 + j
    u32 w1p[4][4];
    #pragma unroll
    for (int kb = 0; kb < 4; kb++)
        #pragma unroll
        for (int jj = 0; jj < 4; jj++) {
            int f = kb * 32 + q * 8 + jj * 2;
            w1p[kb][jj] = (u32)f2bf(ldf(w1, 64 * 128 + f, fl)) |
                          ((u32)f2bf(ldf(w1, 64 * 128 + f + 1, fl)) << 16);
        }
    float csum_r[8], bwp_r[8];
    #pragma unroll
    for (int nb = 0; nb < 8; nb++) {
        csum_r[nb] = csum[nb * 16 + m];
        bwp_r[nb]  = bwp[nb * 16 + m];
    }
    float g2c[8], b2n[8];
    #pragma unroll
    for (int nb = 0; nb < 8; nb++) {
        g2c[nb] = ldf(lng, nb * 16 + m, fl);
        b2n[nb] = ldf(lnb, nb * 16 + m, fl);
    }
    __syncthreads();

    f32x4 zf = {0.f, 0.f, 0.f, 0.f};
    int stride = gridDim.x * 4;
    for (int node = blockIdx.x * 4 + w; node < N_NODES; node += stride) {
        int rs = rowst[node], re = rowst[node + 1];
        float hacc[8];
        #pragma unroll
        for (int nb = 0; nb < 8; nb++) hacc[nb] = 0.f;
        float V = 0.f;

        for (int base = rs; base < re; base += 16) {
            int idx = base + m;
            int eidx = (idx < re) ? idx : (re - 1);
            int eid = eids[eidx];
            int srcn = srcp[eid];
            float av = eaf[eid];

            const u16* yrow = y + (size_t)srcn * 128 + q * 8;
            bf16x8 afrag[4];
            float s1 = 0.f, s2 = 0.f;
            #pragma unroll
            for (int kb = 0; kb < 4; kb++) {
                bf16x8 yv = *(const bf16x8*)(yrow + kb * 32);
                #pragma unroll
                for (int j = 0; j < 8; j++) {
                    float wv = bf2f((u16)((w1p[kb][j >> 1] >> ((j & 1) * 16)) & 0xffff));
                    float vv = fmaxf(fmaf(av, wv, bf2f((u16)yv[j])), 0.f);
                    s1 += vv; s2 = fmaf(vv, vv, s2);
                    afrag[kb][j] = (short)f2bf(vv);
                }
            }
            s1 += __shfl_xor(s1, 16); s2 += __shfl_xor(s2, 16);
            s1 += __shfl_xor(s1, 32); s2 += __shfl_xor(s2, 32);
            float mu = s1 * (1.f / 128.f);
            float rsd = rsqrtf(s2 * (1.f / 128.f) - mu * mu + 1e-5f);

            f32x4 acc[8];
            #pragma unroll
            for (int nb = 0; nb < 8; nb++) acc[nb] = zf;
            #pragma unroll
            for (int nb = 0; nb < 8; nb++) {
                const u16* brow = &sB[(nb * 16 + m) * 136 + q * 8];
                #pragma unroll
                for (int kb = 0; kb < 4; kb++) {
                    bf16x8 bfrag = *(const bf16x8*)(brow + kb * 32);
                    acc[nb] = __builtin_amdgcn_mfma_f32_16x16x32_bf16(afrag[kb], bfrag, acc[nb], 0, 0, 0);
                }
            }
            // per-edge epilogue: C -> relu -> LN2 stats -> masked accumulate
            #pragma unroll
            for (int r = 0; r < 4; r++) {
                int e = q * 4 + r;
                float murow = __shfl(mu, e);
                float rsrow = __shfl(rsd, e);
                float z[8]; float t1 = 0.f, t2 = 0.f;
                #pragma unroll
                for (int nb = 0; nb < 8; nb++) {
                    float cval = fmaf(rsrow, fmaf(-murow, csum_r[nb], acc[nb][r]), bwp_r[nb]);
                    float zz = fmaxf(cval, 0.f);
                    z[nb] = zz; t1 += zz; t2 = fmaf(zz, zz, t2);
                }
                #pragma unroll
                for (int o = 1; o < 16; o <<= 1) { t1 += __shfl_xor(t1, o); t2 += __shfl_xor(t2, o); }
                float mu2 = t1 * (1.f / 128.f);
                float rs2 = rsqrtf(t2 * (1.f / 128.f) - mu2 * mu2 + 1e-5f);
                if (base + e >= re) rs2 = 0.f;   // mask pad edges
                V = fmaf(mu2, rs2, V);
                #pragma unroll
                for (int nb = 0; nb < 8; nb++) hacc[nb] = fmaf(rs2, z[nb], hacc[nb]);
            }
        }
        // cross-quad reduce and single store
        #pragma unroll
        for (int nb = 0; nb < 8; nb++) {
            hacc[nb] += __shfl_xor(hacc[nb], 16);
            hacc[nb] += __shfl_xor(hacc[nb], 32);
        }
        V += __shfl_xor(V, 16); V += __shfl_xor(V, 32);
        if (q == 0) {
            float dg = (float)(re - rs);
            #pragma unroll
            for (int nb = 0; nb < 8; nb++) {
                int f2 = nb * 16 + m;
                h1[(size_t)node * 128 + f2] = fmaf(g2c[nb], hacc[nb] - V, dg * b2n[nb]);
            }
        }
    }
}

// ---------------- fused q/k/v/skip projection GEMM ----------------
__global__ __launch_bounds__(256) void k_proj(
    const float* __restrict__ hin, const u16* __restrict__ wt,
    const float* __restrict__ bcat, u16* __restrict__ outp)
{
    __shared__ u16 sA[64 * 136];
    __shared__ u16 sB[128 * 136];
    int t = threadIdx.x;
    int l = t & 63, w = t >> 6;
    int m = l & 15, q = l >> 4;
    int rowbase = blockIdx.x * 64;
    for (int c = t; c < 64 * 32; c += 256) {
        int row = c >> 5, ch = c & 31;
        int gr = rowbase + row;
        float4 v;
        if (gr < N_NODES) v = *(const float4*)&hin[(size_t)gr * 128 + ch * 4];
        else v = make_float4(0.f, 0.f, 0.f, 0.f);
        ushort4 pk;
        pk.x = f2bf(v.x); pk.y = f2bf(v.y); pk.z = f2bf(v.z); pk.w = f2bf(v.w);
        *(ushort4*)&sA[row * 136 + ch * 4] = pk;
    }
    __syncthreads();
    bf16x8 afrag[4];
    #pragma unroll
    for (int kb = 0; kb < 4; kb++)
        afrag[kb] = *(const bf16x8*)&sA[(w * 16 + m) * 136 + kb * 32 + q * 8];

    f32x4 zf = {0.f, 0.f, 0.f, 0.f};
    for (int g = 0; g < 4; ++g) {
        __syncthreads();
        for (int c = t; c < 128 * 32; c += 256) {
            int row = c >> 5, ch = c & 31;
            *(ushort4*)&sB[row * 136 + ch * 4] = *(const ushort4*)&wt[(g * 128 + row) * 128 + ch * 4];
        }
        __syncthreads();
        f32x4 acc[8];
        #pragma unroll
        for (int nb = 0; nb < 8; nb++) acc[nb] = zf;
        #pragma unroll
        for (int nb = 0; nb < 8; nb++) {
            const u16* brow = &sB[(nb * 16 + m) * 136 + q * 8];
            #pragma unroll
            for (int kb = 0; kb < 4; kb++) {
                bf16x8 bfrag = *(const bf16x8*)(brow + kb * 32);
                acc[nb] = __builtin_amdgcn_mfma_f32_16x16x32_bf16(afrag[kb], bfrag, acc[nb], 0, 0, 0);
            }
        }
        #pragma unroll
        for (int nb = 0; nb < 8; nb++) {
            int col = g * 128 + nb * 16 + m;
            float bb = bcat[col];
            #pragma unroll
            for (int r = 0; r < 4; r++) {
                int row = rowbase + w * 16 + q * 4 + r;
                if (row < N_NODES) outp[(size_t)row * 512 + col] = f2bf(acc[nb][r] + bb);
            }
        }
    }
}

// ---------------- attention: wave per dst node, 4 edge-slots x 16 lanes ----------------
// lane16 = l&15 handles 8 features; head = lane16>>2; slot sub = l>>4 processes
// every-4th edge with an independent online-softmax stream; streams merged at end.
__global__ __launch_bounds__(256) void k_attn(
    const u16* __restrict__ qkvs,
    const int* __restrict__ rowst, const int* __restrict__ eids,
    const int* __restrict__ srcp, const float* __restrict__ eaf,
    const void* __restrict__ wep, float* __restrict__ hout,
    const int* __restrict__ flag)
{
    int fl = getflag(flag);
    int t = threadIdx.x;
    int l = t & 63, w = t >> 6;
    int dstn = blockIdx.x * 4 + w;        // grid*4 == N exactly
    int lane16 = l & 15, sub = l >> 4;
    int f0 = lane16 * 8;                  // 8 features per lane
    const float scale = 0.17677669529663687f;  // 1/sqrt(32)

    bf16x8 q8 = *(const bf16x8*)&qkvs[(size_t)dstn * 512 + f0];
    float qf[8], wef[8];
    #pragma unroll
    for (int j = 0; j < 8; j++) {
        qf[j] = bf2f((u16)q8[j]) * scale;
        wef[j] = ldf(wep, f0 + j, fl);
    }
    float mi = -1e30f, si = 0.f;
    float a8[8];
    #pragma unroll
    for (int j = 0; j < 8; j++) a8[j] = 0.f;

    int rs = rowst[dstn], re = rowst[dstn + 1];
    for (int i = rs + sub; i < re; i += 4) {
        int eid = eids[i];
        int sn = srcp[eid];
        float av = eaf[eid];
        const u16* srow = &qkvs[(size_t)sn * 512 + f0];
        bf16x8 k8 = *(const bf16x8*)(srow + 128);
        bf16x8 v8 = *(const bf16x8*)(srow + 256);
        float p = 0.f;
        float ve[8];
        #pragma unroll
        for (int j = 0; j < 8; j++) {
            float kv = fmaf(av, wef[j], bf2f((u16)k8[j]));
            p = fmaf(qf[j], kv, p);
            ve[j] = fmaf(av, wef[j], bf2f((u16)v8[j]));
        }
        p += __shfl_xor(p, 1); p += __shfl_xor(p, 2);   // sum over head's 4 lanes
        float mn = fmaxf(mi, p);
        float fs = __expf(mi - mn);
        float pe = __expf(p - mn);
        si = fmaf(si, fs, pe);
        #pragma unroll
        for (int j = 0; j < 8; j++) a8[j] = fmaf(a8[j], fs, pe * ve[j]);
        mi = mn;
    }
    // merge the 4 sub-streams (online-softmax state merge, xor 16 then 32)
    #pragma unroll
    for (int off = 16; off < 64; off <<= 1) {
        float mo = __shfl_xor(mi, off);
        float so = __shfl_xor(si, off);
        float mm = fmaxf(mi, mo);
        float f1 = __expf(mi - mm);
        float f2 = __expf(mo - mm);
        si = si * f1 + so * f2;
        #pragma unroll
        for (int j = 0; j < 8; j++) {
            float ao = __shfl_xor(a8[j], off);
            a8[j] = a8[j] * f1 + ao * f2;
        }
        mi = mm;
    }
    if (sub == 0) {
        float inv = 1.f / (si + 1e-16f);
        bf16x8 s8 = *(const bf16x8*)&qkvs[(size_t)dstn * 512 + 384 + f0];
        float4 o0, o1;
        float o[8];
        #pragma unroll
        for (int j = 0; j < 8; j++)
            o[j] = fmaxf(fmaf(a8[j], inv, bf2f((u16)s8[j])), 0.f);
        o0.x = o[0]; o0.y = o[1]; o0.z = o[2]; o0.w = o[3];
        o1.x = o[4]; o1.y = o[5]; o1.z = o[6]; o1.w = o[7];
        float* hr = hout + (size_t)dstn * 128 + f0;
        *(float4*)hr = o0;
        *(float4*)(hr + 4) = o1;
    }
}

// ---------------- global mean pool ----------------
__global__ __launch_bounds__(256) void k_pool(
    const float* __restrict__ h, const int* __restrict__ batch,
    float* __restrict__ gsum, float* __restrict__ gcnt)
{
    __shared__ float ssum[8 * 128];
    __shared__ float scnt[8];
    int t = threadIdx.x;
    for (int i = t; i < 8 * 128; i += 256) ssum[i] = 0.f;
    if (t < 8) scnt[t] = 0.f;
    __syncthreads();
    int f = t & 127, half = t >> 7;
    int per = (N_NODES + gridDim.x - 1) / gridDim.x;
    int lo = blockIdx.x * per;
    int hi = lo + per; if (hi > N_NODES) hi = N_NODES;
    float racc = 0.f; float rcnt = 0.f; int rg = -1;
    for (int n = lo + half; n < hi; n += 2) {
        int g = batch[n];
        if (g != rg) {
            if (rg >= 0) { atomicAdd(&ssum[rg * 128 + f], racc); if (f == 0) atomicAdd(&scnt[rg], rcnt); }
            rg = g; racc = 0.f; rcnt = 0.f;
        }
        racc += h[(size_t)n * 128 + f];
        rcnt += 1.f;
    }
    if (rg >= 0) { atomicAdd(&ssum[rg * 128 + f], racc); if (f == 0) atomicAdd(&scnt[rg], rcnt); }
    __syncthreads();
    for (int i = t; i < 8 * 128; i += 256) unsafeAtomicAdd(&gsum[i], ssum[i]);
    if (t < 8) unsafeAtomicAdd(&gcnt[t], scnt[t]);
}

__global__ void k_out(const float* __restrict__ gsum, const float* __restrict__ gcnt,
                      void* __restrict__ outp, const int* __restrict__ flag) {
    int fl = getflag(flag);
    int t = threadIdx.x;  // 1024
    float c = fmaxf(gcnt[t >> 7], 1.f);
    float v = gsum[t] / c;
    if (fl) ((float*)outp)[t] = v;
    else ((u16*)outp)[t] = f2bf(v);
}

extern "C" void kernel_launch(void* const* d_in, const int* in_sizes, int n_in,
                              void* d_out, int out_size, void* d_ws, size_t ws_size,
                              hipStream_t stream)
{
    (void)in_sizes; (void)n_in; (void)out_size; (void)ws_size;
    const void* x    = d_in[0];
    const int* ei    = (const int*)d_in[1];
    const void* ea   = d_in[2];
    const int* batch = (const int*)d_in[3];
    const void* w1   = d_in[4];
    const void* b1   = d_in[5];
    const void* lng  = d_in[6];
    const void* lnb  = d_in[7];
    const void* w2   = d_in[8];
    const void* b2   = d_in[9];
    const int* srcp = ei;
    const int* dstp = ei + N_EDGES;

    char* wsb = (char*)d_ws;
    size_t cur = 0;
    auto alloc = [&](size_t sz) -> void* {
        void* p = wsb + cur;
        cur += (sz + 255) & ~(size_t)255;
        return p;
    };
    u16*   y      = (u16*)  alloc((size_t)N_NODES * 128 * 2);   // bf16 lin1 output
    float* h1     = (float*)alloc((size_t)N_NODES * 128 * 4);   // reused as h3
    float* h2     = (float*)alloc((size_t)N_NODES * 128 * 4);
    u16*   qkvs   = (u16*)  alloc((size_t)N_NODES * 512 * 2);
    float* eaf    = (float*)alloc((size_t)N_EDGES * 4);
    u16*   gt     = (u16*)  alloc(128 * 128 * 2);
    u16*   wcat1  = (u16*)  alloc(512 * 128 * 2);
    u16*   wcat2  = (u16*)  alloc(512 * 128 * 2);
    float* csum   = (float*)alloc(128 * 4);
    float* bwp    = (float*)alloc(128 * 4);
    float* bcat1  = (float*)alloc(512 * 4);
    float* bcat2  = (float*)alloc(512 * 4);
    int*   cntdeg = (int*)  alloc((size_t)N_NODES * 4);
    int*   rowst  = (int*)  alloc((size_t)(N_NODES + 1) * 4);
    int*   nxt    = (int*)  alloc((size_t)N_NODES * 4);
    int*   eids   = (int*)  alloc((size_t)N_EDGES * 4);
    float* gsum   = (float*)alloc((8 * 128 + 8) * 4);
    int*   dtflag = (int*)  alloc(256);
    float* h3 = h1;   // h1 is dead after first k_proj

    hipMemsetAsync(cntdeg, 0, (size_t)N_NODES * 4, stream);
    hipMemsetAsync(gsum, 0, (8 * 128 + 8) * 4, stream);

    k_detect<<<1, 256, 0, stream>>>((const u16*)x, dtflag);
    k_canon_ea<<<3125, 256, 0, stream>>>(ea, eaf, dtflag);

    P8 pw; P8 pb;
    pw.s[0] = d_in[10]; pw.s[1] = d_in[12]; pw.s[2] = d_in[14]; pw.s[3] = d_in[17];
    pw.s[4] = d_in[19]; pw.s[5] = d_in[21]; pw.s[6] = d_in[23]; pw.s[7] = d_in[26];
    pb.s[0] = d_in[11]; pb.s[1] = d_in[13]; pb.s[2] = d_in[15]; pb.s[3] = d_in[18];
    pb.s[4] = d_in[20]; pb.s[5] = d_in[22]; pb.s[6] = d_in[24]; pb.s[7] = d_in[27];
    k_transpose8<<<512, 256, 0, stream>>>(pw, wcat1, wcat2, dtflag);
    k_bcat8<<<4, 256, 0, stream>>>(pb, bcat1, bcat2, dtflag);
    k_prep_w2<<<1, 128, 0, stream>>>(w2, lng, lnb, b2, gt, csum, bwp, dtflag);

    k_embed_lin1<<<782, 256, 0, stream>>>(x, w1, b1, y, dtflag);
    k_degree<<<3125, 256, 0, stream>>>(dstp, cntdeg);
    k_scan<<<1, 1024, 0, stream>>>(cntdeg, rowst, nxt);
    k_scatter<<<3125, 256, 0, stream>>>(dstp, nxt, eids);
    k_embed_edges<<<2048, 256, 0, stream>>>(y, srcp, eaf, rowst, eids,
                                            w1, lng, lnb, gt, csum, bwp, h1, dtflag);
    k_proj<<<782, 256, 0, stream>>>(h1, wcat1, bcat1, qkvs);
    k_attn<<<12500, 256, 0, stream>>>(qkvs, rowst, eids, srcp, eaf, d_in[16], h2, dtflag);
    k_proj<<<782, 256, 0, stream>>>(h2, wcat2, bcat2, qkvs);
    k_attn<<<12500, 256, 0, stream>>>(qkvs, rowst, eids, srcp, eaf, d_in[25], h3, dtflag);
    k_pool<<<128, 256, 0, stream>>>(h3, batch, gsum, gsum + 8 * 128);
    k_out<<<1, 1024, 0, stream>>>(gsum, gsum + 8 * 128, d_out, dtflag);
}

// Round 6
// 977.998 us; speedup vs baseline: 1.6432x; 1.0287x over previous
//
#include <hip/hip_runtime.h>

typedef unsigned short u16;
typedef unsigned int u32;
typedef __attribute__((ext_vector_type(8))) short bf16x8;
typedef __attribute__((ext_vector_type(4))) float f32x4;

#define N_NODES 50000
#define N_EDGES 800000

__device__ __forceinline__ float bf2f(u16 u) {
    union { u32 i; float f; } v; v.i = ((u32)u) << 16; return v.f;
}
__device__ __forceinline__ u16 f2bf(float f) {
    union { u32 i; float f; } v; v.f = f;
    u32 i = v.i;
    return (u16)((i + 0x7FFFu + ((i >> 16) & 1u)) >> 16);
}
// dtype-agnostic load: fl!=0 -> float32 buffer, else bf16 (u16) buffer
__device__ __forceinline__ float ldf(const void* p, int i, int fl) {
    return fl ? ((const float*)p)[i] : bf2f(((const u16*)p)[i]);
}
__device__ __forceinline__ int getflag(const int* flag) {
    return __builtin_amdgcn_readfirstlane(*flag);
}

// ---------------- dtype detection ----------------
__global__ void k_detect(const u16* __restrict__ xr, int* __restrict__ flag) {
    __shared__ int sc[256];
    int t = threadIdx.x;
    int c = 0;
    for (int i = t; i < 4096; i += 256) {
        u32 e = (xr[i] >> 7) & 0xFF;
        if (e >= 143) c++;
    }
    sc[t] = c;
    __syncthreads();
    for (int s = 128; s > 0; s >>= 1) {
        if (t < s) sc[t] += sc[t + s];
        __syncthreads();
    }
    if (t == 0) *flag = (sc[0] > 64) ? 1 : 0;   // 1 = float32, 0 = bf16
}

// ---------------- weight prep ----------------
struct P8 { const void* s[8]; };

__global__ void k_transpose8(P8 p, u16* __restrict__ dst0, u16* __restrict__ dst1,
                             const int* __restrict__ flag) {
    int fl = getflag(flag);
    int gid = blockIdx.x * 256 + threadIdx.x;   // 512 blocks -> 8 * 16384
    int wi = gid >> 14;
    int id = gid & 16383;
    int k = id >> 7, n = id & 127;
    u16* d = (wi < 4) ? (dst0 + wi * 16384) : (dst1 + (wi - 4) * 16384);
    d[n * 128 + k] = f2bf(ldf(p.s[wi], id, fl));
}

__global__ void k_bcat8(P8 p, float* __restrict__ out1, float* __restrict__ out2,
                        const int* __restrict__ flag) {
    int fl = getflag(flag);
    int t = blockIdx.x * 256 + threadIdx.x;   // 4 blocks -> 1024
    float v = ldf(p.s[t >> 7], t & 127, fl);
    if (t < 512) out1[t] = v; else out2[t - 512] = v;
}

// G = diag(lng)*W2 folded; csum[n] = sum_f G[f,n]; bwp[n] = sum_f lnb_f*W2[f,n] + b2[n]
// also packs the W1 edge row (row 64) as bf16 pairs into w1pk[64]
__global__ void k_prep_w2(const void* __restrict__ w2, const void* __restrict__ lng_,
                          const void* __restrict__ lnb_, const void* __restrict__ b2_,
                          const void* __restrict__ w1, u16* __restrict__ gt,
                          float* __restrict__ csum, float* __restrict__ bwp,
                          u32* __restrict__ w1pk, const int* __restrict__ flag)
{
    int fl = getflag(flag);
    int t = threadIdx.x;   // 128 threads, 1 block; t = output column n
    if (t < 128) {
        float cs = 0.f, bw = 0.f;
        for (int f = 0; f < 128; f++) {
            float wv = ldf(w2, f * 128 + t, fl);
            float g = ldf(lng_, f, fl);
            float b = ldf(lnb_, f, fl);
            u16 gwq = f2bf(g * wv);
            gt[t * 128 + f] = gwq;
            cs += bf2f(gwq);
            bw = fmaf(b, wv, bw);
        }
        csum[t] = cs;
        bwp[t] = bw + ldf(b2_, t, fl);
        if (t < 64)
            w1pk[t] = (u32)f2bf(ldf(w1, 64 * 128 + t * 2, fl)) |
                      ((u32)f2bf(ldf(w1, 64 * 128 + t * 2 + 1, fl)) << 16);
    }
}

// ---------------- embed: node-side lin1  y = x @ W1[:64] + b1  (bf16 out) ----------------
__global__ __launch_bounds__(256) void k_embed_lin1(
    const void* __restrict__ x, const void* __restrict__ w1,
    const void* __restrict__ b1, u16* __restrict__ y,
    const int* __restrict__ flag)
{
    __shared__ float sx[2][64];
    int fl = getflag(flag);
    int t = threadIdx.x;
    int col = t & 127, half = t >> 7;
    float wreg[64];
    #pragma unroll
    for (int k = 0; k < 64; k++) wreg[k] = ldf(w1, k * 128 + col, fl);
    float bias = ldf(b1, col, fl);
    int base = blockIdx.x * 64;
    for (int it = 0; it < 32; ++it) {
        __syncthreads();
        if (t < 128) {
            int nh = base + it * 2 + (t >> 6);
            sx[t >> 6][t & 63] = (nh < N_NODES) ? ldf(x, nh * 64 + (t & 63), fl) : 0.f;
        }
        __syncthreads();
        float acc = bias;
        #pragma unroll
        for (int k = 0; k < 64; k++) acc = fmaf(sx[half][k], wreg[k], acc);
        int n = base + it * 2 + half;
        if (n < N_NODES) y[(size_t)n * 128 + col] = f2bf(acc);
    }
}

// ---------------- CSR build ----------------
__global__ void k_degree(const int* __restrict__ dst, int* __restrict__ cnt) {
    int e = blockIdx.x * 256 + threadIdx.x;
    if (e < N_EDGES) atomicAdd(&cnt[dst[e]], 1);
}

__global__ __launch_bounds__(1024) void k_scan(const int* __restrict__ cnt,
                                               int* __restrict__ row_start,
                                               int* __restrict__ nxt)
{
    __shared__ int wsum[16];
    __shared__ int s_tot;
    int t = threadIdx.x, lane = t & 63, wid = t >> 6;
    int run = 0;
    for (int base = 0; base < N_NODES; base += 8192) {
        int i0 = base + t * 8;
        int v[8], pre[8];
        int s = 0;
        #pragma unroll
        for (int j = 0; j < 8; j++) {
            int i = i0 + j;
            v[j] = (i < N_NODES) ? cnt[i] : 0;
            pre[j] = s;
            s += v[j];
        }
        int tsum = s;
        int sc = tsum;
        #pragma unroll
        for (int off = 1; off < 64; off <<= 1) {
            int o = __shfl_up(sc, off);
            if (lane >= off) sc += o;
        }
        if (lane == 63) wsum[wid] = sc;
        __syncthreads();
        if (t == 0) {
            int acc2 = 0;
            #pragma unroll
            for (int k2 = 0; k2 < 16; k2++) { int vv = wsum[k2]; wsum[k2] = acc2; acc2 += vv; }
            s_tot = acc2;
        }
        __syncthreads();
        int texcl = run + wsum[wid] + (sc - tsum);
        #pragma unroll
        for (int j = 0; j < 8; j++) {
            int i = i0 + j;
            if (i < N_NODES) { int ex = texcl + pre[j]; row_start[i] = ex; nxt[i] = ex; }
        }
        run += s_tot;
        __syncthreads();
    }
    if (t == 0) row_start[N_NODES] = run;
}

// scatter edges into CSR order carrying (src, edge_attr) payload — removes the
// eids->srcp->eaf indirection chain from both hot loops (sequential int2 reads).
__global__ void k_scatter(const int* __restrict__ dst, const int* __restrict__ srcp,
                          const void* __restrict__ ea, int* __restrict__ nxt,
                          int2* __restrict__ csr, const int* __restrict__ flag) {
    int fl = getflag(flag);
    int e = blockIdx.x * 256 + threadIdx.x;
    if (e < N_EDGES) {
        int p = atomicAdd(&nxt[dst[e]], 1);
        int2 v;
        v.x = srcp[e];
        v.y = __float_as_int(ldf(ea, e, fl));
        csr[p] = v;
    }
}

// ---------------- embed: persistent wave-per-node per-edge MLP, register aggregation ----------------
// LN1 affine folded into B (G = diag(g)W2); LN2 affine folded out of aggregation.
// csr payload read sequentially + next-chunk prefetch; w1 edge row in LDS (VGPR diet).
__global__ __launch_bounds__(256) void k_embed_edges(
    const u16* __restrict__ y, const int2* __restrict__ csr,
    const int* __restrict__ rowst,
    const void* __restrict__ lng, const void* __restrict__ lnb,
    const u16* __restrict__ gt, const u32* __restrict__ w1pk,
    const float* __restrict__ csum, const float* __restrict__ bwp,
    float* __restrict__ h1, const int* __restrict__ flag)
{
    __shared__ u16 sB[128 * 136];   // G^T, padded rows (2-way bank conflict = free)
    __shared__ u32 sW1[64];         // packed bf16 pairs of W1 edge row
    int fl = getflag(flag);
    int t = threadIdx.x;
    for (int c = t; c < 128 * 32; c += 256) {
        int row = c >> 5, ch = c & 31;
        *(ushort4*)&sB[row * 136 + ch * 4] = *(const ushort4*)&gt[row * 128 + ch * 4];
    }
    if (t < 64) sW1[t] = w1pk[t];
    int l = t & 63, w = t >> 6;
    int m = l & 15, q = l >> 4;

    float csum_r[8], bwp_r[8];
    #pragma unroll
    for (int nb = 0; nb < 8; nb++) {
        csum_r[nb] = csum[nb * 16 + m];
        bwp_r[nb]  = bwp[nb * 16 + m];
    }
    __syncthreads();

    f32x4 zf = {0.f, 0.f, 0.f, 0.f};
    int stride = gridDim.x * 4;
    for (int node = blockIdx.x * 4 + w; node < N_NODES; node += stride) {
        int rs = rowst[node], re = rowst[node + 1];
        float hacc[8];
        #pragma unroll
        for (int nb = 0; nb < 8; nb++) hacc[nb] = 0.f;
        float V = 0.f;
        if (rs < re) {
            int idx = rs + m;
            int2 sa = csr[(idx < re) ? idx : (re - 1)];
            for (int base = rs; base < re; base += 16) {
                int2 cur = sa;
                int nbase = base + 16;
                if (nbase < re) {
                    int ni = nbase + m;
                    sa = csr[(ni < re) ? ni : (re - 1)];
                }
                int srcn = cur.x;
                float av = __int_as_float(cur.y);

                const u16* yrow = y + (size_t)srcn * 128 + q * 8;
                bf16x8 afrag[4];
                float s1 = 0.f, s2 = 0.f;
                #pragma unroll
                for (int kb = 0; kb < 4; kb++) {
                    bf16x8 yv = *(const bf16x8*)(yrow + kb * 32);
                    const u32* wr = &sW1[kb * 16 + q * 4];
                    #pragma unroll
                    for (int j = 0; j < 8; j++) {
                        float wv = bf2f((u16)((wr[j >> 1] >> ((j & 1) * 16)) & 0xffff));
                        float vv = fmaxf(fmaf(av, wv, bf2f((u16)yv[j])), 0.f);
                        s1 += vv; s2 = fmaf(vv, vv, s2);
                        afrag[kb][j] = (short)f2bf(vv);
                    }
                }
                s1 += __shfl_xor(s1, 16); s2 += __shfl_xor(s2, 16);
                s1 += __shfl_xor(s1, 32); s2 += __shfl_xor(s2, 32);
                float mu = s1 * (1.f / 128.f);
                float rsd = rsqrtf(s2 * (1.f / 128.f) - mu * mu + 1e-5f);

                f32x4 acc[8];
                #pragma unroll
                for (int nb = 0; nb < 8; nb++) acc[nb] = zf;
                #pragma unroll
                for (int nb = 0; nb < 8; nb++) {
                    const u16* brow = &sB[(nb * 16 + m) * 136 + q * 8];
                    #pragma unroll
                    for (int kb = 0; kb < 4; kb++) {
                        bf16x8 bfrag = *(const bf16x8*)(brow + kb * 32);
                        acc[nb] = __builtin_amdgcn_mfma_f32_16x16x32_bf16(afrag[kb], bfrag, acc[nb], 0, 0, 0);
                    }
                }
                // per-edge epilogue: C -> relu -> LN2 stats -> masked accumulate
                #pragma unroll
                for (int r = 0; r < 4; r++) {
                    int e = q * 4 + r;
                    float murow = __shfl(mu, e);
                    float rsrow = __shfl(rsd, e);
                    float z[8]; float t1 = 0.f, t2 = 0.f;
                    #pragma unroll
                    for (int nb = 0; nb < 8; nb++) {
                        float cval = fmaf(rsrow, fmaf(-murow, csum_r[nb], acc[nb][r]), bwp_r[nb]);
                        float zz = fmaxf(cval, 0.f);
                        z[nb] = zz; t1 += zz; t2 = fmaf(zz, zz, t2);
                    }
                    #pragma unroll
                    for (int o = 1; o < 16; o <<= 1) { t1 += __shfl_xor(t1, o); t2 += __shfl_xor(t2, o); }
                    float mu2 = t1 * (1.f / 128.f);
                    float rs2 = rsqrtf(t2 * (1.f / 128.f) - mu2 * mu2 + 1e-5f);
                    if (base + e >= re) rs2 = 0.f;   // mask pad edges
                    V = fmaf(mu2, rs2, V);
                    #pragma unroll
                    for (int nb = 0; nb < 8; nb++) hacc[nb] = fmaf(rs2, z[nb], hacc[nb]);
                }
            }
        }
        // cross-quad reduce and single store
        #pragma unroll
        for (int nb = 0; nb < 8; nb++) {
            hacc[nb] += __shfl_xor(hacc[nb], 16);
            hacc[nb] += __shfl_xor(hacc[nb], 32);
        }
        V += __shfl_xor(V, 16); V += __shfl_xor(V, 32);
        if (q == 0) {
            float dg = (float)(re - rs);
            #pragma unroll
            for (int nb = 0; nb < 8; nb++) {
                int f2 = nb * 16 + m;
                float gg = ldf(lng, f2, fl), bb = ldf(lnb, f2, fl);
                h1[(size_t)node * 128 + f2] = fmaf(gg, hacc[nb] - V, dg * bb);
            }
        }
    }
}

// ---------------- fused q/k/v/skip projection GEMM ----------------
__global__ __launch_bounds__(256) void k_proj(
    const float* __restrict__ hin, const u16* __restrict__ wt,
    const float* __restrict__ bcat, u16* __restrict__ outp)
{
    __shared__ u16 sA[64 * 136];
    __shared__ u16 sB[128 * 136];
    int t = threadIdx.x;
    int l = t & 63, w = t >> 6;
    int m = l & 15, q = l >> 4;
    int rowbase = blockIdx.x * 64;
    for (int c = t; c < 64 * 32; c += 256) {
        int row = c >> 5, ch = c & 31;
        int gr = rowbase + row;
        float4 v;
        if (gr < N_NODES) v = *(const float4*)&hin[(size_t)gr * 128 + ch * 4];
        else v = make_float4(0.f, 0.f, 0.f, 0.f);
        ushort4 pk;
        pk.x = f2bf(v.x); pk.y = f2bf(v.y); pk.z = f2bf(v.z); pk.w = f2bf(v.w);
        *(ushort4*)&sA[row * 136 + ch * 4] = pk;
    }
    __syncthreads();
    bf16x8 afrag[4];
    #pragma unroll
    for (int kb = 0; kb < 4; kb++)
        afrag[kb] = *(const bf16x8*)&sA[(w * 16 + m) * 136 + kb * 32 + q * 8];

    f32x4 zf = {0.f, 0.f, 0.f, 0.f};
    for (int g = 0; g < 4; ++g) {
        __syncthreads();
        for (int c = t; c < 128 * 32; c += 256) {
            int row = c >> 5, ch = c & 31;
            *(ushort4*)&sB[row * 136 + ch * 4] = *(const ushort4*)&wt[(g * 128 + row) * 128 + ch * 4];
        }
        __syncthreads();
        f32x4 acc[8];
        #pragma unroll
        for (int nb = 0; nb < 8; nb++) acc[nb] = zf;
        #pragma unroll
        for (int nb = 0; nb < 8; nb++) {
            const u16* brow = &sB[(nb * 16 + m) * 136 + q * 8];
            #pragma unroll
            for (int kb = 0; kb < 4; kb++) {
                bf16x8 bfrag = *(const bf16x8*)(brow + kb * 32);
                acc[nb] = __builtin_amdgcn_mfma_f32_16x16x32_bf16(afrag[kb], bfrag, acc[nb], 0, 0, 0);
            }
        }
        #pragma unroll
        for (int nb = 0; nb < 8; nb++) {
            int col = g * 128 + nb * 16 + m;
            float bb = bcat[col];
            #pragma unroll
            for (int r = 0; r < 4; r++) {
                int row = rowbase + w * 16 + q * 4 + r;
                if (row < N_NODES) outp[(size_t)row * 512 + col] = f2bf(acc[nb][r] + bb);
            }
        }
    }
}

// ---------------- attention: wave per dst node, 4 edge-slots x 16 lanes ----------------
__global__ __launch_bounds__(256) void k_attn(
    const u16* __restrict__ qkvs,
    const int* __restrict__ rowst, const int2* __restrict__ csr,
    const void* __restrict__ wep, float* __restrict__ hout,
    const int* __restrict__ flag)
{
    int fl = getflag(flag);
    int t = threadIdx.x;
    int l = t & 63, w = t >> 6;
    int dstn = blockIdx.x * 4 + w;        // grid*4 == N exactly
    int lane16 = l & 15, sub = l >> 4;
    int f0 = lane16 * 8;                  // 8 features per lane
    const float scale = 0.17677669529663687f;  // 1/sqrt(32)

    bf16x8 q8 = *(const bf16x8*)&qkvs[(size_t)dstn * 512 + f0];
    float qf[8], wef[8];
    #pragma unroll
    for (int j = 0; j < 8; j++) {
        qf[j] = bf2f((u16)q8[j]) * scale;
        wef[j] = ldf(wep, f0 + j, fl);
    }
    float mi = -1e30f, si = 0.f;
    float a8[8];
    #pragma unroll
    for (int j = 0; j < 8; j++) a8[j] = 0.f;

    int rs = rowst[dstn], re = rowst[dstn + 1];
    for (int i = rs + sub; i < re; i += 4) {
        int2 sa = csr[i];
        int sn = sa.x;
        float av = __int_as_float(sa.y);
        const u16* srow = &qkvs[(size_t)sn * 512 + f0];
        bf16x8 k8 = *(const bf16x8*)(srow + 128);
        bf16x8 v8 = *(const bf16x8*)(srow + 256);
        float p = 0.f;
        float ve[8];
        #pragma unroll
        for (int j = 0; j < 8; j++) {
            float kv = fmaf(av, wef[j], bf2f((u16)k8[j]));
            p = fmaf(qf[j], kv, p);
            ve[j] = fmaf(av, wef[j], bf2f((u16)v8[j]));
        }
        p += __shfl_xor(p, 1); p += __shfl_xor(p, 2);   // sum over head's 4 lanes
        float mn = fmaxf(mi, p);
        float fs = __expf(mi - mn);
        float pe = __expf(p - mn);
        si = fmaf(si, fs, pe);
        #pragma unroll
        for (int j = 0; j < 8; j++) a8[j] = fmaf(a8[j], fs, pe * ve[j]);
        mi = mn;
    }
    // merge the 4 sub-streams (online-softmax state merge, xor 16 then 32)
    #pragma unroll
    for (int off = 16; off < 64; off <<= 1) {
        float mo = __shfl_xor(mi, off);
        float so = __shfl_xor(si, off);
        float mm = fmaxf(mi, mo);
        float f1 = __expf(mi - mm);
        float f2 = __expf(mo - mm);
        si = si * f1 + so * f2;
        #pragma unroll
        for (int j = 0; j < 8; j++) {
            float ao = __shfl_xor(a8[j], off);
            a8[j] = a8[j] * f1 + ao * f2;
        }
        mi = mm;
    }
    if (sub == 0) {
        float inv = 1.f / (si + 1e-16f);
        bf16x8 s8 = *(const bf16x8*)&qkvs[(size_t)dstn * 512 + 384 + f0];
        float4 o0, o1;
        float o[8];
        #pragma unroll
        for (int j = 0; j < 8; j++)
            o[j] = fmaxf(fmaf(a8[j], inv, bf2f((u16)s8[j])), 0.f);
        o0.x = o[0]; o0.y = o[1]; o0.z = o[2]; o0.w = o[3];
        o1.x = o[4]; o1.y = o[5]; o1.z = o[6]; o1.w = o[7];
        float* hr = hout + (size_t)dstn * 128 + f0;
        *(float4*)hr = o0;
        *(float4*)(hr + 4) = o1;
    }
}

// ---------------- global mean pool ----------------
__global__ __launch_bounds__(256) void k_pool(
    const float* __restrict__ h, const int* __restrict__ batch,
    float* __restrict__ gsum, float* __restrict__ gcnt)
{
    __shared__ float ssum[8 * 128];
    __shared__ float scnt[8];
    int t = threadIdx.x;
    for (int i = t; i < 8 * 128; i += 256) ssum[i] = 0.f;
    if (t < 8) scnt[t] = 0.f;
    __syncthreads();
    int f = t & 127, half = t >> 7;
    int per = (N_NODES + gridDim.x - 1) / gridDim.x;
    int lo = blockIdx.x * per;
    int hi = lo + per; if (hi > N_NODES) hi = N_NODES;
    float racc = 0.f; float rcnt = 0.f; int rg = -1;
    for (int n = lo + half; n < hi; n += 2) {
        int g = batch[n];
        if (g != rg) {
            if (rg >= 0) { atomicAdd(&ssum[rg * 128 + f], racc); if (f == 0) atomicAdd(&scnt[rg], rcnt); }
            rg = g; racc = 0.f; rcnt = 0.f;
        }
        racc += h[(size_t)n * 128 + f];
        rcnt += 1.f;
    }
    if (rg >= 0) { atomicAdd(&ssum[rg * 128 + f], racc); if (f == 0) atomicAdd(&scnt[rg], rcnt); }
    __syncthreads();
    for (int i = t; i < 8 * 128; i += 256) unsafeAtomicAdd(&gsum[i], ssum[i]);
    if (t < 8) unsafeAtomicAdd(&gcnt[t], scnt[t]);
}

__global__ void k_out(const float* __restrict__ gsum, const float* __restrict__ gcnt,
                      void* __restrict__ outp, const int* __restrict__ flag) {
    int fl = getflag(flag);
    int t = threadIdx.x;  // 1024
    float c = fmaxf(gcnt[t >> 7], 1.f);
    float v = gsum[t] / c;
    if (fl) ((float*)outp)[t] = v;
    else ((u16*)outp)[t] = f2bf(v);
}

extern "C" void kernel_launch(void* const* d_in, const int* in_sizes, int n_in,
                              void* d_out, int out_size, void* d_ws, size_t ws_size,
                              hipStream_t stream)
{
    (void)in_sizes; (void)n_in; (void)out_size; (void)ws_size;
    const void* x    = d_in[0];
    const int* ei    = (const int*)d_in[1];
    const void* ea   = d_in[2];
    const int* batch = (const int*)d_in[3];
    const void* w1   = d_in[4];
    const void* b1   = d_in[5];
    const void* lng  = d_in[6];
    const void* lnb  = d_in[7];
    const void* w2   = d_in[8];
    const void* b2   = d_in[9];
    const int* srcp = ei;
    const int* dstp = ei + N_EDGES;

    char* wsb = (char*)d_ws;
    size_t cur = 0;
    auto alloc = [&](size_t sz) -> void* {
        void* p = wsb + cur;
        cur += (sz + 255) & ~(size_t)255;
        return p;
    };
    u16*   y      = (u16*)  alloc((size_t)N_NODES * 128 * 2);   // bf16 lin1 output
    float* h1     = (float*)alloc((size_t)N_NODES * 128 * 4);   // reused as h3
    float* h2     = (float*)alloc((size_t)N_NODES * 128 * 4);
    u16*   qkvs   = (u16*)  alloc((size_t)N_NODES * 512 * 2);
    int2*  csr    = (int2*) alloc((size_t)N_EDGES * 8);
    u16*   gt     = (u16*)  alloc(128 * 128 * 2);
    u16*   wcat1  = (u16*)  alloc(512 * 128 * 2);
    u16*   wcat2  = (u16*)  alloc(512 * 128 * 2);
    float* csum   = (float*)alloc(128 * 4);
    float* bwp    = (float*)alloc(128 * 4);
    u32*   w1pk   = (u32*)  alloc(64 * 4);
    float* bcat1  = (float*)alloc(512 * 4);
    float* bcat2  = (float*)alloc(512 * 4);
    int*   cntdeg = (int*)  alloc((size_t)N_NODES * 4);
    int*   rowst  = (int*)  alloc((size_t)(N_NODES + 1) * 4);
    int*   nxt    = (int*)  alloc((size_t)N_NODES * 4);
    float* gsum   = (float*)alloc((8 * 128 + 8) * 4);
    int*   dtflag = (int*)  alloc(256);
    float* h3 = h1;   // h1 is dead after first k_proj

    hipMemsetAsync(cntdeg, 0, (size_t)N_NODES * 4, stream);
    hipMemsetAsync(gsum, 0, (8 * 128 + 8) * 4, stream);

    k_detect<<<1, 256, 0, stream>>>((const u16*)x, dtflag);

    P8 pw; P8 pb;
    pw.s[0] = d_in[10]; pw.s[1] = d_in[12]; pw.s[2] = d_in[14]; pw.s[3] = d_in[17];
    pw.s[4] = d_in[19]; pw.s[5] = d_in[21]; pw.s[6] = d_in[23]; pw.s[7] = d_in[26];
    pb.s[0] = d_in[11]; pb.s[1] = d_in[13]; pb.s[2] = d_in[15]; pb.s[3] = d_in[18];
    pb.s[4] = d_in[20]; pb.s[5] = d_in[22]; pb.s[6] = d_in[24]; pb.s[7] = d_in[27];
    k_transpose8<<<512, 256, 0, stream>>>(pw, wcat1, wcat2, dtflag);
    k_bcat8<<<4, 256, 0, stream>>>(pb, bcat1, bcat2, dtflag);
    k_prep_w2<<<1, 128, 0, stream>>>(w2, lng, lnb, b2, w1, gt, csum, bwp, w1pk, dtflag);

    k_embed_lin1<<<782, 256, 0, stream>>>(x, w1, b1, y, dtflag);
    k_degree<<<3125, 256, 0, stream>>>(dstp, cntdeg);
    k_scan<<<1, 1024, 0, stream>>>(cntdeg, rowst, nxt);
    k_scatter<<<3125, 256, 0, stream>>>(dstp, srcp, ea, nxt, csr, dtflag);
    k_embed_edges<<<2048, 256, 0, stream>>>(y, csr, rowst, lng, lnb,
                                            gt, w1pk, csum, bwp, h1, dtflag);
    k_proj<<<782, 256, 0, stream>>>(h1, wcat1, bcat1, qkvs);
    k_attn<<<12500, 256, 0, stream>>>(qkvs, rowst, csr, d_in[16], h2, dtflag);
    k_proj<<<782, 256, 0, stream>>>(h2, wcat2, bcat2, qkvs);
    k_attn<<<12500, 256, 0, stream>>>(qkvs, rowst, csr, d_in[25], h3, dtflag);
    k_pool<<<128, 256, 0, stream>>>(h3, batch, gsum, gsum + 8 * 128);
    k_out<<<1, 1024, 0, stream>>>(gsum, gsum + 8 * 128, d_out, dtflag);
}

// Round 7
// 970.375 us; speedup vs baseline: 1.6561x; 1.0079x over previous
//
#include <hip/hip_runtime.h>

typedef unsigned short u16;
typedef unsigned int u32;
typedef __attribute__((ext_vector_type(8))) short bf16x8;
typedef __attribute__((ext_vector_type(4))) float f32x4;

#define N_NODES 50000
#define N_EDGES 800000

__device__ __forceinline__ float bf2f(u16 u) {
    union { u32 i; float f; } v; v.i = ((u32)u) << 16; return v.f;
}
__device__ __forceinline__ u16 f2bf(float f) {
    union { u32 i; float f; } v; v.f = f;
    u32 i = v.i;
    return (u16)((i + 0x7FFFu + ((i >> 16) & 1u)) >> 16);
}
// dtype-agnostic load: fl!=0 -> float32 buffer, else bf16 (u16) buffer
__device__ __forceinline__ float ldf(const void* p, int i, int fl) {
    return fl ? ((const float*)p)[i] : bf2f(((const u16*)p)[i]);
}
__device__ __forceinline__ int getflag(const int* flag) {
    return __builtin_amdgcn_readfirstlane(*flag);
}

// ---------------- dtype detection ----------------
__global__ void k_detect(const u16* __restrict__ xr, int* __restrict__ flag) {
    __shared__ int sc[256];
    int t = threadIdx.x;
    int c = 0;
    for (int i = t; i < 4096; i += 256) {
        u32 e = (xr[i] >> 7) & 0xFF;
        if (e >= 143) c++;
    }
    sc[t] = c;
    __syncthreads();
    for (int s = 128; s > 0; s >>= 1) {
        if (t < s) sc[t] += sc[t + s];
        __syncthreads();
    }
    if (t == 0) *flag = (sc[0] > 64) ? 1 : 0;   // 1 = float32, 0 = bf16
}

// ---------------- weight prep ----------------
struct P8 { const void* s[8]; };

__global__ void k_transpose8(P8 p, u16* __restrict__ dst0, u16* __restrict__ dst1,
                             const int* __restrict__ flag) {
    int fl = getflag(flag);
    int gid = blockIdx.x * 256 + threadIdx.x;   // 512 blocks -> 8 * 16384
    int wi = gid >> 14;
    int id = gid & 16383;
    int k = id >> 7, n = id & 127;
    u16* d = (wi < 4) ? (dst0 + wi * 16384) : (dst1 + (wi - 4) * 16384);
    d[n * 128 + k] = f2bf(ldf(p.s[wi], id, fl));
}

__global__ void k_bcat8(P8 p, float* __restrict__ out1, float* __restrict__ out2,
                        const int* __restrict__ flag) {
    int fl = getflag(flag);
    int t = blockIdx.x * 256 + threadIdx.x;   // 4 blocks -> 1024
    float v = ldf(p.s[t >> 7], t & 127, fl);
    if (t < 512) out1[t] = v; else out2[t - 512] = v;
}

// G = diag(lng)*W2 folded; csum[n] = sum_f G[f,n]; bwp[n] = sum_f lnb_f*W2[f,n] + b2[n]
// also packs the W1 edge row (row 64) as bf16 pairs into w1pk[64]
__global__ void k_prep_w2(const void* __restrict__ w2, const void* __restrict__ lng_,
                          const void* __restrict__ lnb_, const void* __restrict__ b2_,
                          const void* __restrict__ w1, u16* __restrict__ gt,
                          float* __restrict__ csum, float* __restrict__ bwp,
                          u32* __restrict__ w1pk, const int* __restrict__ flag)
{
    int fl = getflag(flag);
    int t = threadIdx.x;   // 128 threads, 1 block; t = output column n
    if (t < 128) {
        float cs = 0.f, bw = 0.f;
        for (int f = 0; f < 128; f++) {
            float wv = ldf(w2, f * 128 + t, fl);
            float g = ldf(lng_, f, fl);
            float b = ldf(lnb_, f, fl);
            u16 gwq = f2bf(g * wv);
            gt[t * 128 + f] = gwq;
            cs += bf2f(gwq);
            bw = fmaf(b, wv, bw);
        }
        csum[t] = cs;
        bwp[t] = bw + ldf(b2_, t, fl);
        if (t < 64)
            w1pk[t] = (u32)f2bf(ldf(w1, 64 * 128 + t * 2, fl)) |
                      ((u32)f2bf(ldf(w1, 64 * 128 + t * 2 + 1, fl)) << 16);
    }
}

// ---------------- embed: node-side lin1  y = x @ W1[:64] + b1  (bf16 out) ----------------
__global__ __launch_bounds__(256) void k_embed_lin1(
    const void* __restrict__ x, const void* __restrict__ w1,
    const void* __restrict__ b1, u16* __restrict__ y,
    const int* __restrict__ flag)
{
    __shared__ float sx[2][64];
    int fl = getflag(flag);
    int t = threadIdx.x;
    int col = t & 127, half = t >> 7;
    float wreg[64];
    #pragma unroll
    for (int k = 0; k < 64; k++) wreg[k] = ldf(w1, k * 128 + col, fl);
    float bias = ldf(b1, col, fl);
    int base = blockIdx.x * 64;
    for (int it = 0; it < 32; ++it) {
        __syncthreads();
        if (t < 128) {
            int nh = base + it * 2 + (t >> 6);
            sx[t >> 6][t & 63] = (nh < N_NODES) ? ldf(x, nh * 64 + (t & 63), fl) : 0.f;
        }
        __syncthreads();
        float acc = bias;
        #pragma unroll
        for (int k = 0; k < 64; k++) acc = fmaf(sx[half][k], wreg[k], acc);
        int n = base + it * 2 + half;
        if (n < N_NODES) y[(size_t)n * 128 + col] = f2bf(acc);
    }
}

// ---------------- CSR build ----------------
__global__ void k_degree(const int* __restrict__ dst, int* __restrict__ cnt) {
    int e = blockIdx.x * 256 + threadIdx.x;
    if (e < N_EDGES) atomicAdd(&cnt[dst[e]], 1);
}

__global__ __launch_bounds__(1024) void k_scan(const int* __restrict__ cnt,
                                               int* __restrict__ row_start,
                                               int* __restrict__ nxt)
{
    __shared__ int wsum[16];
    __shared__ int s_tot;
    int t = threadIdx.x, lane = t & 63, wid = t >> 6;
    int run = 0;
    for (int base = 0; base < N_NODES; base += 8192) {
        int i0 = base + t * 8;
        int v[8], pre[8];
        int s = 0;
        #pragma unroll
        for (int j = 0; j < 8; j++) {
            int i = i0 + j;
            v[j] = (i < N_NODES) ? cnt[i] : 0;
            pre[j] = s;
            s += v[j];
        }
        int tsum = s;
        int sc = tsum;
        #pragma unroll
        for (int off = 1; off < 64; off <<= 1) {
            int o = __shfl_up(sc, off);
            if (lane >= off) sc += o;
        }
        if (lane == 63) wsum[wid] = sc;
        __syncthreads();
        if (t == 0) {
            int acc2 = 0;
            #pragma unroll
            for (int k2 = 0; k2 < 16; k2++) { int vv = wsum[k2]; wsum[k2] = acc2; acc2 += vv; }
            s_tot = acc2;
        }
        __syncthreads();
        int texcl = run + wsum[wid] + (sc - tsum);
        #pragma unroll
        for (int j = 0; j < 8; j++) {
            int i = i0 + j;
            if (i < N_NODES) { int ex = texcl + pre[j]; row_start[i] = ex; nxt[i] = ex; }
        }
        run += s_tot;
        __syncthreads();
    }
    if (t == 0) row_start[N_NODES] = run;
}

// scatter edges into CSR order carrying (src, edge_attr) payload
__global__ void k_scatter(const int* __restrict__ dst, const int* __restrict__ srcp,
                          const void* __restrict__ ea, int* __restrict__ nxt,
                          int2* __restrict__ csr, const int* __restrict__ flag) {
    int fl = getflag(flag);
    int e = blockIdx.x * 256 + threadIdx.x;
    if (e < N_EDGES) {
        int p = atomicAdd(&nxt[dst[e]], 1);
        int2 v;
        v.x = srcp[e];
        v.y = __float_as_int(ldf(ea, e, fl));
        csr[p] = v;
    }
}

// ---------------- embed: persistent wave-per-node per-edge MLP, register aggregation ----------------
// Software-pipelined: next chunk's csr + y-row loads issue right after the A-stage
// consumes the current yv, so their latency hides under MFMA + epilogue.
__global__ __launch_bounds__(256) void k_embed_edges(
    const u16* __restrict__ y, const int2* __restrict__ csr,
    const int* __restrict__ rowst,
    const void* __restrict__ lng, const void* __restrict__ lnb,
    const u16* __restrict__ gt, const u32* __restrict__ w1pk,
    const float* __restrict__ csum, const float* __restrict__ bwp,
    u16* __restrict__ h1, const int* __restrict__ flag)
{
    __shared__ u16 sB[128 * 136];   // G^T, padded rows (2-way bank conflict = free)
    __shared__ u32 sW1[64];         // packed bf16 pairs of W1 edge row
    int fl = getflag(flag);
    int t = threadIdx.x;
    for (int c = t; c < 128 * 32; c += 256) {
        int row = c >> 5, ch = c & 31;
        *(ushort4*)&sB[row * 136 + ch * 4] = *(const ushort4*)&gt[row * 128 + ch * 4];
    }
    if (t < 64) sW1[t] = w1pk[t];
    int l = t & 63, w = t >> 6;
    int m = l & 15, q = l >> 4;

    float csum_r[8], bwp_r[8];
    #pragma unroll
    for (int nb = 0; nb < 8; nb++) {
        csum_r[nb] = csum[nb * 16 + m];
        bwp_r[nb]  = bwp[nb * 16 + m];
    }
    __syncthreads();

    f32x4 zf = {0.f, 0.f, 0.f, 0.f};
    int stride = gridDim.x * 4;
    for (int node = blockIdx.x * 4 + w; node < N_NODES; node += stride) {
        int rs = rowst[node], re = rowst[node + 1];
        float hacc[8];
        #pragma unroll
        for (int nb = 0; nb < 8; nb++) hacc[nb] = 0.f;
        float V = 0.f;
        if (rs < re) {
            // pipeline prologue: first chunk's csr + y rows
            int idx = rs + m;
            int2 sa = csr[(idx < re) ? idx : (re - 1)];
            bf16x8 yv[4];
            {
                const u16* yr = y + (size_t)sa.x * 128 + q * 8;
                #pragma unroll
                for (int kb = 0; kb < 4; kb++) yv[kb] = *(const bf16x8*)(yr + kb * 32);
            }
            for (int base = rs; base < re; base += 16) {
                float av = __int_as_float(sa.y);
                // A-stage: consume yv into afrag + LN1 stats
                bf16x8 afrag[4];
                float s1 = 0.f, s2 = 0.f;
                #pragma unroll
                for (int kb = 0; kb < 4; kb++) {
                    const u32* wr = &sW1[kb * 16 + q * 4];
                    #pragma unroll
                    for (int j = 0; j < 8; j++) {
                        float wv = bf2f((u16)((wr[j >> 1] >> ((j & 1) * 16)) & 0xffff));
                        float vv = fmaxf(fmaf(av, wv, bf2f((u16)yv[kb][j])), 0.f);
                        s1 += vv; s2 = fmaf(vv, vv, s2);
                        afrag[kb][j] = (short)f2bf(vv);
                    }
                }
                // issue NEXT chunk's loads now — latency hides under MFMA+epilogue
                int nbase = base + 16;
                if (nbase < re) {
                    int ni = nbase + m;
                    sa = csr[(ni < re) ? ni : (re - 1)];
                    const u16* yr = y + (size_t)sa.x * 128 + q * 8;
                    #pragma unroll
                    for (int kb = 0; kb < 4; kb++) yv[kb] = *(const bf16x8*)(yr + kb * 32);
                }
                s1 += __shfl_xor(s1, 16); s2 += __shfl_xor(s2, 16);
                s1 += __shfl_xor(s1, 32); s2 += __shfl_xor(s2, 32);
                float mu = s1 * (1.f / 128.f);
                float rsd = rsqrtf(s2 * (1.f / 128.f) - mu * mu + 1e-5f);

                f32x4 acc[8];
                #pragma unroll
                for (int nb = 0; nb < 8; nb++) acc[nb] = zf;
                #pragma unroll
                for (int nb = 0; nb < 8; nb++) {
                    const u16* brow = &sB[(nb * 16 + m) * 136 + q * 8];
                    #pragma unroll
                    for (int kb = 0; kb < 4; kb++) {
                        bf16x8 bfrag = *(const bf16x8*)(brow + kb * 32);
                        acc[nb] = __builtin_amdgcn_mfma_f32_16x16x32_bf16(afrag[kb], bfrag, acc[nb], 0, 0, 0);
                    }
                }
                // per-edge epilogue: C -> relu -> LN2 stats -> masked accumulate
                #pragma unroll
                for (int r = 0; r < 4; r++) {
                    int e = q * 4 + r;
                    float murow = __shfl(mu, e);
                    float rsrow = __shfl(rsd, e);
                    float z[8]; float t1 = 0.f, t2 = 0.f;
                    #pragma unroll
                    for (int nb = 0; nb < 8; nb++) {
                        float cval = fmaf(rsrow, fmaf(-murow, csum_r[nb], acc[nb][r]), bwp_r[nb]);
                        float zz = fmaxf(cval, 0.f);
                        z[nb] = zz; t1 += zz; t2 = fmaf(zz, zz, t2);
                    }
                    #pragma unroll
                    for (int o = 1; o < 16; o <<= 1) { t1 += __shfl_xor(t1, o); t2 += __shfl_xor(t2, o); }
                    float mu2 = t1 * (1.f / 128.f);
                    float rs2 = rsqrtf(t2 * (1.f / 128.f) - mu2 * mu2 + 1e-5f);
                    if (base + e >= re) rs2 = 0.f;   // mask pad edges
                    V = fmaf(mu2, rs2, V);
                    #pragma unroll
                    for (int nb = 0; nb < 8; nb++) hacc[nb] = fmaf(rs2, z[nb], hacc[nb]);
                }
            }
        }
        // cross-quad reduce and single store (bf16)
        #pragma unroll
        for (int nb = 0; nb < 8; nb++) {
            hacc[nb] += __shfl_xor(hacc[nb], 16);
            hacc[nb] += __shfl_xor(hacc[nb], 32);
        }
        V += __shfl_xor(V, 16); V += __shfl_xor(V, 32);
        if (q == 0) {
            float dg = (float)(re - rs);
            #pragma unroll
            for (int nb = 0; nb < 8; nb++) {
                int f2 = nb * 16 + m;
                float gg = ldf(lng, f2, fl), bb = ldf(lnb, f2, fl);
                h1[(size_t)node * 128 + f2] = f2bf(fmaf(gg, hacc[nb] - V, dg * bb));
            }
        }
    }
}

// ---------------- fused q/k/v/skip projection GEMM (bf16 h input) ----------------
__global__ __launch_bounds__(256) void k_proj(
    const u16* __restrict__ hin, const u16* __restrict__ wt,
    const float* __restrict__ bcat, u16* __restrict__ outp)
{
    __shared__ u16 sA[64 * 136];
    __shared__ u16 sB[128 * 136];
    int t = threadIdx.x;
    int l = t & 63, w = t >> 6;
    int m = l & 15, q = l >> 4;
    int rowbase = blockIdx.x * 64;
    for (int c = t; c < 64 * 32; c += 256) {
        int row = c >> 5, ch = c & 31;
        int gr = rowbase + row;
        ushort4 pk = make_ushort4(0, 0, 0, 0);
        if (gr < N_NODES) pk = *(const ushort4*)&hin[(size_t)gr * 128 + ch * 4];
        *(ushort4*)&sA[row * 136 + ch * 4] = pk;
    }
    __syncthreads();
    bf16x8 afrag[4];
    #pragma unroll
    for (int kb = 0; kb < 4; kb++)
        afrag[kb] = *(const bf16x8*)&sA[(w * 16 + m) * 136 + kb * 32 + q * 8];

    f32x4 zf = {0.f, 0.f, 0.f, 0.f};
    for (int g = 0; g < 4; ++g) {
        __syncthreads();
        for (int c = t; c < 128 * 32; c += 256) {
            int row = c >> 5, ch = c & 31;
            *(ushort4*)&sB[row * 136 + ch * 4] = *(const ushort4*)&wt[(g * 128 + row) * 128 + ch * 4];
        }
        __syncthreads();
        f32x4 acc[8];
        #pragma unroll
        for (int nb = 0; nb < 8; nb++) acc[nb] = zf;
        #pragma unroll
        for (int nb = 0; nb < 8; nb++) {
            const u16* brow = &sB[(nb * 16 + m) * 136 + q * 8];
            #pragma unroll
            for (int kb = 0; kb < 4; kb++) {
                bf16x8 bfrag = *(const bf16x8*)(brow + kb * 32);
                acc[nb] = __builtin_amdgcn_mfma_f32_16x16x32_bf16(afrag[kb], bfrag, acc[nb], 0, 0, 0);
            }
        }
        #pragma unroll
        for (int nb = 0; nb < 8; nb++) {
            int col = g * 128 + nb * 16 + m;
            float bb = bcat[col];
            #pragma unroll
            for (int r = 0; r < 4; r++) {
                int row = rowbase + w * 16 + q * 4 + r;
                if (row < N_NODES) outp[(size_t)row * 512 + col] = f2bf(acc[nb][r] + bb);
            }
        }
    }
}

// ---------------- attention: wave per dst node, 4 edge-slots x 16 lanes, prefetched ----------------
__global__ __launch_bounds__(256) void k_attn(
    const u16* __restrict__ qkvs,
    const int* __restrict__ rowst, const int2* __restrict__ csr,
    const void* __restrict__ wep, u16* __restrict__ hout,
    const int* __restrict__ flag)
{
    int fl = getflag(flag);
    int t = threadIdx.x;
    int l = t & 63, w = t >> 6;
    int dstn = blockIdx.x * 4 + w;        // grid*4 == N exactly
    int lane16 = l & 15, sub = l >> 4;
    int f0 = lane16 * 8;                  // 8 features per lane
    const float scale = 0.17677669529663687f;  // 1/sqrt(32)

    bf16x8 q8 = *(const bf16x8*)&qkvs[(size_t)dstn * 512 + f0];
    float qf[8], wef[8];
    #pragma unroll
    for (int j = 0; j < 8; j++) {
        qf[j] = bf2f((u16)q8[j]) * scale;
        wef[j] = ldf(wep, f0 + j, fl);
    }
    float mi = -1e30f, si = 0.f;
    float a8[8];
    #pragma unroll
    for (int j = 0; j < 8; j++) a8[j] = 0.f;

    int rs = rowst[dstn], re = rowst[dstn + 1];
    int i = rs + sub;
    int2 sa;
    bf16x8 k8, v8;
    if (i < re) {
        sa = csr[i];
        const u16* sr = &qkvs[(size_t)sa.x * 512 + f0];
        k8 = *(const bf16x8*)(sr + 128);
        v8 = *(const bf16x8*)(sr + 256);
    }
    for (; i < re; i += 4) {
        float av = __int_as_float(sa.y);
        // consume k8/v8 into p and ve[] first
        float p = 0.f;
        float ve[8];
        #pragma unroll
        for (int j = 0; j < 8; j++) {
            float kv = fmaf(av, wef[j], bf2f((u16)k8[j]));
            p = fmaf(qf[j], kv, p);
            ve[j] = fmaf(av, wef[j], bf2f((u16)v8[j]));
        }
        // prefetch next edge's rows — hides under shuffle/exp chain
        if (i + 4 < re) {
            sa = csr[i + 4];
            const u16* sr = &qkvs[(size_t)sa.x * 512 + f0];
            k8 = *(const bf16x8*)(sr + 128);
            v8 = *(const bf16x8*)(sr + 256);
        }
        p += __shfl_xor(p, 1); p += __shfl_xor(p, 2);   // sum over head's 4 lanes
        float mn = fmaxf(mi, p);
        float fs = __expf(mi - mn);
        float pe = __expf(p - mn);
        si = fmaf(si, fs, pe);
        #pragma unroll
        for (int j = 0; j < 8; j++) a8[j] = fmaf(a8[j], fs, pe * ve[j]);
        mi = mn;
    }
    // merge the 4 sub-streams (online-softmax state merge, xor 16 then 32)
    #pragma unroll
    for (int off = 16; off < 64; off <<= 1) {
        float mo = __shfl_xor(mi, off);
        float so = __shfl_xor(si, off);
        float mm = fmaxf(mi, mo);
        float f1 = __expf(mi - mm);
        float f2 = __expf(mo - mm);
        si = si * f1 + so * f2;
        #pragma unroll
        for (int j = 0; j < 8; j++) {
            float ao = __shfl_xor(a8[j], off);
            a8[j] = a8[j] * f1 + ao * f2;
        }
        mi = mm;
    }
    if (sub == 0) {
        float inv = 1.f / (si + 1e-16f);
        bf16x8 s8 = *(const bf16x8*)&qkvs[(size_t)dstn * 512 + 384 + f0];
        ushort4 p0, p1;
        float o[8];
        #pragma unroll
        for (int j = 0; j < 8; j++)
            o[j] = fmaxf(fmaf(a8[j], inv, bf2f((u16)s8[j])), 0.f);
        p0.x = f2bf(o[0]); p0.y = f2bf(o[1]); p0.z = f2bf(o[2]); p0.w = f2bf(o[3]);
        p1.x = f2bf(o[4]); p1.y = f2bf(o[5]); p1.z = f2bf(o[6]); p1.w = f2bf(o[7]);
        u16* hr = hout + (size_t)dstn * 128 + f0;
        *(ushort4*)hr = p0;
        *(ushort4*)(hr + 4) = p1;
    }
}

// ---------------- global mean pool (bf16 h input) ----------------
__global__ __launch_bounds__(256) void k_pool(
    const u16* __restrict__ h, const int* __restrict__ batch,
    float* __restrict__ gsum, float* __restrict__ gcnt)
{
    __shared__ float ssum[8 * 128];
    __shared__ float scnt[8];
    int t = threadIdx.x;
    for (int i = t; i < 8 * 128; i += 256) ssum[i] = 0.f;
    if (t < 8) scnt[t] = 0.f;
    __syncthreads();
    int f = t & 127, half = t >> 7;
    int per = (N_NODES + gridDim.x - 1) / gridDim.x;
    int lo = blockIdx.x * per;
    int hi = lo + per; if (hi > N_NODES) hi = N_NODES;
    float racc = 0.f; float rcnt = 0.f; int rg = -1;
    for (int n = lo + half; n < hi; n += 2) {
        int g = batch[n];
        if (g != rg) {
            if (rg >= 0) { atomicAdd(&ssum[rg * 128 + f], racc); if (f == 0) atomicAdd(&scnt[rg], rcnt); }
            rg = g; racc = 0.f; rcnt = 0.f;
        }
        racc += bf2f(h[(size_t)n * 128 + f]);
        rcnt += 1.f;
    }
    if (rg >= 0) { atomicAdd(&ssum[rg * 128 + f], racc); if (f == 0) atomicAdd(&scnt[rg], rcnt); }
    __syncthreads();
    for (int i = t; i < 8 * 128; i += 256) unsafeAtomicAdd(&gsum[i], ssum[i]);
    if (t < 8) unsafeAtomicAdd(&gcnt[t], scnt[t]);
}

__global__ void k_out(const float* __restrict__ gsum, const float* __restrict__ gcnt,
                      void* __restrict__ outp, const int* __restrict__ flag) {
    int fl = getflag(flag);
    int t = threadIdx.x;  // 1024
    float c = fmaxf(gcnt[t >> 7], 1.f);
    float v = gsum[t] / c;
    if (fl) ((float*)outp)[t] = v;
    else ((u16*)outp)[t] = f2bf(v);
}

extern "C" void kernel_launch(void* const* d_in, const int* in_sizes, int n_in,
                              void* d_out, int out_size, void* d_ws, size_t ws_size,
                              hipStream_t stream)
{
    (void)in_sizes; (void)n_in; (void)out_size; (void)ws_size;
    const void* x    = d_in[0];
    const int* ei    = (const int*)d_in[1];
    const void* ea   = d_in[2];
    const int* batch = (const int*)d_in[3];
    const void* w1   = d_in[4];
    const void* b1   = d_in[5];
    const void* lng  = d_in[6];
    const void* lnb  = d_in[7];
    const void* w2   = d_in[8];
    const void* b2   = d_in[9];
    const int* srcp = ei;
    const int* dstp = ei + N_EDGES;

    char* wsb = (char*)d_ws;
    size_t cur = 0;
    auto alloc = [&](size_t sz) -> void* {
        void* p = wsb + cur;
        cur += (sz + 255) & ~(size_t)255;
        return p;
    };
    u16*   y      = (u16*)  alloc((size_t)N_NODES * 128 * 2);   // bf16 lin1 output
    u16*   h1     = (u16*)  alloc((size_t)N_NODES * 128 * 2);   // bf16; reused as h3
    u16*   h2     = (u16*)  alloc((size_t)N_NODES * 128 * 2);   // bf16
    u16*   qkvs   = (u16*)  alloc((size_t)N_NODES * 512 * 2);
    int2*  csr    = (int2*) alloc((size_t)N_EDGES * 8);
    u16*   gt     = (u16*)  alloc(128 * 128 * 2);
    u16*   wcat1  = (u16*)  alloc(512 * 128 * 2);
    u16*   wcat2  = (u16*)  alloc(512 * 128 * 2);
    float* csum   = (float*)alloc(128 * 4);
    float* bwp    = (float*)alloc(128 * 4);
    u32*   w1pk   = (u32*)  alloc(64 * 4);
    float* bcat1  = (float*)alloc(512 * 4);
    float* bcat2  = (float*)alloc(512 * 4);
    int*   cntdeg = (int*)  alloc((size_t)N_NODES * 4);
    int*   rowst  = (int*)  alloc((size_t)(N_NODES + 1) * 4);
    int*   nxt    = (int*)  alloc((size_t)N_NODES * 4);
    float* gsum   = (float*)alloc((8 * 128 + 8) * 4);
    int*   dtflag = (int*)  alloc(256);
    u16*   h3 = h1;   // h1 is dead after first k_proj

    hipMemsetAsync(cntdeg, 0, (size_t)N_NODES * 4, stream);
    hipMemsetAsync(gsum, 0, (8 * 128 + 8) * 4, stream);

    k_detect<<<1, 256, 0, stream>>>((const u16*)x, dtflag);

    P8 pw; P8 pb;
    pw.s[0] = d_in[10]; pw.s[1] = d_in[12]; pw.s[2] = d_in[14]; pw.s[3] = d_in[17];
    pw.s[4] = d_in[19]; pw.s[5] = d_in[21]; pw.s[6] = d_in[23]; pw.s[7] = d_in[26];
    pb.s[0] = d_in[11]; pb.s[1] = d_in[13]; pb.s[2] = d_in[15]; pb.s[3] = d_in[18];
    pb.s[4] = d_in[20]; pb.s[5] = d_in[22]; pb.s[6] = d_in[24]; pb.s[7] = d_in[27];
    k_transpose8<<<512, 256, 0, stream>>>(pw, wcat1, wcat2, dtflag);
    k_bcat8<<<4, 256, 0, stream>>>(pb, bcat1, bcat2, dtflag);
    k_prep_w2<<<1, 128, 0, stream>>>(w2, lng, lnb, b2, w1, gt, csum, bwp, w1pk, dtflag);

    k_embed_lin1<<<782, 256, 0, stream>>>(x, w1, b1, y, dtflag);
    k_degree<<<3125, 256, 0, stream>>>(dstp, cntdeg);
    k_scan<<<1, 1024, 0, stream>>>(cntdeg, rowst, nxt);
    k_scatter<<<3125, 256, 0, stream>>>(dstp, srcp, ea, nxt, csr, dtflag);
    k_embed_edges<<<2048, 256, 0, stream>>>(y, csr, rowst, lng, lnb,
                                            gt, w1pk, csum, bwp, h1, dtflag);
    k_proj<<<782, 256, 0, stream>>>(h1, wcat1, bcat1, qkvs);
    k_attn<<<12500, 256, 0, stream>>>(qkvs, rowst, csr, d_in[16], h2, dtflag);
    k_proj<<<782, 256, 0, stream>>>(h2, wcat2, bcat2, qkvs);
    k_attn<<<12500, 256, 0, stream>>>(qkvs, rowst, csr, d_in[25], h3, dtflag);
    k_pool<<<128, 256, 0, stream>>>(h3, batch, gsum, gsum + 8 * 128);
    k_out<<<1, 1024, 0, stream>>>(gsum, gsum + 8 * 128, d_out, dtflag);
}

// Round 8
// 961.188 us; speedup vs baseline: 1.6720x; 1.0096x over previous
//
#include <hip/hip_runtime.h>

typedef unsigned short u16;
typedef unsigned int u32;
typedef __attribute__((ext_vector_type(8))) short bf16x8;
typedef __attribute__((ext_vector_type(4))) float f32x4;

#define N_NODES 50000
#define N_EDGES 800000

__device__ __forceinline__ float bf2f(u16 u) {
    union { u32 i; float f; } v; v.i = ((u32)u) << 16; return v.f;
}
__device__ __forceinline__ u16 f2bf(float f) {
    union { u32 i; float f; } v; v.f = f;
    u32 i = v.i;
    return (u16)((i + 0x7FFFu + ((i >> 16) & 1u)) >> 16);
}
// dtype-agnostic load: fl!=0 -> float32 buffer, else bf16 (u16) buffer
__device__ __forceinline__ float ldf(const void* p, int i, int fl) {
    return fl ? ((const float*)p)[i] : bf2f(((const u16*)p)[i]);
}
__device__ __forceinline__ int getflag(const int* flag) {
    return __builtin_amdgcn_readfirstlane(*flag);
}

// ---------------- dtype detection ----------------
__global__ void k_detect(const u16* __restrict__ xr, int* __restrict__ flag) {
    __shared__ int sc[256];
    int t = threadIdx.x;
    int c = 0;
    for (int i = t; i < 4096; i += 256) {
        u32 e = (xr[i] >> 7) & 0xFF;
        if (e >= 143) c++;
    }
    sc[t] = c;
    __syncthreads();
    for (int s = 128; s > 0; s >>= 1) {
        if (t < s) sc[t] += sc[t + s];
        __syncthreads();
    }
    if (t == 0) *flag = (sc[0] > 64) ? 1 : 0;   // 1 = float32, 0 = bf16
}

// ---------------- weight prep ----------------
struct P8 { const void* s[8]; };

__global__ void k_transpose8(P8 p, u16* __restrict__ dst0, u16* __restrict__ dst1,
                             const int* __restrict__ flag) {
    int fl = getflag(flag);
    int gid = blockIdx.x * 256 + threadIdx.x;   // 512 blocks -> 8 * 16384
    int wi = gid >> 14;
    int id = gid & 16383;
    int k = id >> 7, n = id & 127;
    u16* d = (wi < 4) ? (dst0 + wi * 16384) : (dst1 + (wi - 4) * 16384);
    d[n * 128 + k] = f2bf(ldf(p.s[wi], id, fl));
}

__global__ void k_bcat8(P8 p, float* __restrict__ out1, float* __restrict__ out2,
                        const int* __restrict__ flag) {
    int fl = getflag(flag);
    int t = blockIdx.x * 256 + threadIdx.x;   // 4 blocks -> 1024
    float v = ldf(p.s[t >> 7], t & 127, fl);
    if (t < 512) out1[t] = v; else out2[t - 512] = v;
}

// G = diag(lng)*W2 folded; bwp[n] = sum_f lnb_f*W2[f,n] + b2[n]
// also packs the W1 edge row (row 64) as bf16 pairs into w1pk[64]
__global__ void k_prep_w2(const void* __restrict__ w2, const void* __restrict__ lng_,
                          const void* __restrict__ lnb_, const void* __restrict__ b2_,
                          const void* __restrict__ w1, u16* __restrict__ gt,
                          float* __restrict__ bwp,
                          u32* __restrict__ w1pk, const int* __restrict__ flag)
{
    int fl = getflag(flag);
    int t = threadIdx.x;   // 128 threads, 1 block; t = output column n
    if (t < 128) {
        float bw = 0.f;
        for (int f = 0; f < 128; f++) {
            float wv = ldf(w2, f * 128 + t, fl);
            float g = ldf(lng_, f, fl);
            float b = ldf(lnb_, f, fl);
            gt[t * 128 + f] = f2bf(g * wv);
            bw = fmaf(b, wv, bw);
        }
        bwp[t] = bw + ldf(b2_, t, fl);
        if (t < 64)
            w1pk[t] = (u32)f2bf(ldf(w1, 64 * 128 + t * 2, fl)) |
                      ((u32)f2bf(ldf(w1, 64 * 128 + t * 2 + 1, fl)) << 16);
    }
}

// ---------------- embed: node-side lin1  y = x @ W1[:64] + b1  (bf16 out) ----------------
__global__ __launch_bounds__(256) void k_embed_lin1(
    const void* __restrict__ x, const void* __restrict__ w1,
    const void* __restrict__ b1, u16* __restrict__ y,
    const int* __restrict__ flag)
{
    __shared__ float sx[2][64];
    int fl = getflag(flag);
    int t = threadIdx.x;
    int col = t & 127, half = t >> 7;
    float wreg[64];
    #pragma unroll
    for (int k = 0; k < 64; k++) wreg[k] = ldf(w1, k * 128 + col, fl);
    float bias = ldf(b1, col, fl);
    int base = blockIdx.x * 64;
    for (int it = 0; it < 32; ++it) {
        __syncthreads();
        if (t < 128) {
            int nh = base + it * 2 + (t >> 6);
            sx[t >> 6][t & 63] = (nh < N_NODES) ? ldf(x, nh * 64 + (t & 63), fl) : 0.f;
        }
        __syncthreads();
        float acc = bias;
        #pragma unroll
        for (int k = 0; k < 64; k++) acc = fmaf(sx[half][k], wreg[k], acc);
        int n = base + it * 2 + half;
        if (n < N_NODES) y[(size_t)n * 128 + col] = f2bf(acc);
    }
}

// ---------------- CSR build ----------------
__global__ void k_degree(const int* __restrict__ dst, int* __restrict__ cnt) {
    int e = blockIdx.x * 256 + threadIdx.x;
    if (e < N_EDGES) atomicAdd(&cnt[dst[e]], 1);
}

__global__ __launch_bounds__(1024) void k_scan(const int* __restrict__ cnt,
                                               int* __restrict__ row_start,
                                               int* __restrict__ nxt)
{
    __shared__ int wsum[16];
    __shared__ int s_tot;
    int t = threadIdx.x, lane = t & 63, wid = t >> 6;
    int run = 0;
    for (int base = 0; base < N_NODES; base += 8192) {
        int i0 = base + t * 8;
        int v[8], pre[8];
        int s = 0;
        #pragma unroll
        for (int j = 0; j < 8; j++) {
            int i = i0 + j;
            v[j] = (i < N_NODES) ? cnt[i] : 0;
            pre[j] = s;
            s += v[j];
        }
        int tsum = s;
        int sc = tsum;
        #pragma unroll
        for (int off = 1; off < 64; off <<= 1) {
            int o = __shfl_up(sc, off);
            if (lane >= off) sc += o;
        }
        if (lane == 63) wsum[wid] = sc;
        __syncthreads();
        if (t == 0) {
            int acc2 = 0;
            #pragma unroll
            for (int k2 = 0; k2 < 16; k2++) { int vv = wsum[k2]; wsum[k2] = acc2; acc2 += vv; }
            s_tot = acc2;
        }
        __syncthreads();
        int texcl = run + wsum[wid] + (sc - tsum);
        #pragma unroll
        for (int j = 0; j < 8; j++) {
            int i = i0 + j;
            if (i < N_NODES) { int ex = texcl + pre[j]; row_start[i] = ex; nxt[i] = ex; }
        }
        run += s_tot;
        __syncthreads();
    }
    if (t == 0) row_start[N_NODES] = run;
}

// scatter edges into CSR order carrying (src, edge_attr) payload
__global__ void k_scatter(const int* __restrict__ dst, const int* __restrict__ srcp,
                          const void* __restrict__ ea, int* __restrict__ nxt,
                          int2* __restrict__ csr, const int* __restrict__ flag) {
    int fl = getflag(flag);
    int e = blockIdx.x * 256 + threadIdx.x;
    if (e < N_EDGES) {
        int p = atomicAdd(&nxt[dst[e]], 1);
        int2 v;
        v.x = srcp[e];
        v.y = __float_as_int(ldf(ea, e, fl));
        csr[p] = v;
    }
}

// ---------------- embed: wave-per-node, G^T as MFMA A-operand, edges as B ----------------
// Edges live on cols (lane&15), f_out on rows (quad*4+reg). LN1 applied pre-MFMA
// in-lane; LN2 stats = in-register sum + ONE 2-stage butterfly per chunk (was 16
// stages + 8 broadcasts). Node aggregation in registers, one 4-stage
// transpose-reduce per node.
__global__ __launch_bounds__(256) void k_embed_edges(
    const u16* __restrict__ y, const int2* __restrict__ csr,
    const int* __restrict__ rowst,
    const void* __restrict__ lng, const void* __restrict__ lnb,
    const u16* __restrict__ gt, const u32* __restrict__ w1pk,
    const float* __restrict__ bwp,
    u16* __restrict__ h1, const int* __restrict__ flag)
{
    __shared__ u16 sB[128 * 136];   // G^T rows (f_out), padded (2-way conflict = free)
    __shared__ u32 sW1[64];         // packed bf16 pairs of W1 edge row
    int fl = getflag(flag);
    int t = threadIdx.x;
    for (int c = t; c < 128 * 32; c += 256) {
        int row = c >> 5, ch = c & 31;
        *(ushort4*)&sB[row * 136 + ch * 4] = *(const ushort4*)&gt[row * 128 + ch * 4];
    }
    if (t < 64) sW1[t] = w1pk[t];
    int l = t & 63, w = t >> 6;
    int m = l & 15, q = l >> 4;

    // per-lane bias constants at f_out = nb*16 + q*4 + r
    float bwp_r[8][4];
    #pragma unroll
    for (int nb = 0; nb < 8; nb++)
        #pragma unroll
        for (int r = 0; r < 4; r++)
            bwp_r[nb][r] = bwp[nb * 16 + q * 4 + r];
    __syncthreads();

    f32x4 zf = {0.f, 0.f, 0.f, 0.f};
    int stride = gridDim.x * 4;
    for (int node = blockIdx.x * 4 + w; node < N_NODES; node += stride) {
        int rs = rowst[node], re = rowst[node + 1];
        float hacc[8][4];
        #pragma unroll
        for (int nb = 0; nb < 8; nb++)
            #pragma unroll
            for (int r = 0; r < 4; r++) hacc[nb][r] = 0.f;
        float V = 0.f;

        for (int base = rs; base < re; base += 16) {
            int idx = base + m;
            int2 sa = csr[(idx < re) ? idx : (re - 1)];
            float av = __int_as_float(sa.y);
            const u16* yr = y + (size_t)sa.x * 128 + q * 8;
            // A-stage: edge activations (this lane = edge m, f_in = q*8+j+32kb)
            float vv[4][8];
            float s1 = 0.f, s2 = 0.f;
            #pragma unroll
            for (int kb = 0; kb < 4; kb++) {
                bf16x8 yv = *(const bf16x8*)(yr + kb * 32);
                const u32* wr = &sW1[kb * 16 + q * 4];
                #pragma unroll
                for (int j = 0; j < 8; j++) {
                    float wv = bf2f((u16)((wr[j >> 1] >> ((j & 1) * 16)) & 0xffff));
                    float u = fmaxf(fmaf(av, wv, bf2f((u16)yv[j])), 0.f);
                    vv[kb][j] = u;
                    s1 += u; s2 = fmaf(u, u, s2);
                }
            }
            // LN1 stats: reduce over f_in (quad dim) — every lane gets its edge's stats
            s1 += __shfl_xor(s1, 16); s2 += __shfl_xor(s2, 16);
            s1 += __shfl_xor(s1, 32); s2 += __shfl_xor(s2, 32);
            float mu = s1 * (1.f / 128.f);
            float rsd = rsqrtf(s2 * (1.f / 128.f) - mu * mu + 1e-5f);
            float nmu = -mu * rsd;
            // normalize in-lane -> edge B-fragment
            bf16x8 efrag[4];
            #pragma unroll
            for (int kb = 0; kb < 4; kb++)
                #pragma unroll
                for (int j = 0; j < 8; j++)
                    efrag[kb][j] = (short)f2bf(fmaf(vv[kb][j], rsd, nmu));

            f32x4 acc[8];
            #pragma unroll
            for (int nb = 0; nb < 8; nb++) acc[nb] = zf;
            #pragma unroll
            for (int nb = 0; nb < 8; nb++) {
                const u16* grow = &sB[(nb * 16 + m) * 136 + q * 8];
                #pragma unroll
                for (int kb = 0; kb < 4; kb++) {
                    bf16x8 gfrag = *(const bf16x8*)(grow + kb * 32);
                    // G^T as A (M = f_out), edges as B (N = edge)
                    acc[nb] = __builtin_amdgcn_mfma_f32_16x16x32_bf16(gfrag, efrag[kb], acc[nb], 0, 0, 0);
                }
            }
            // LN2 stats: in-register over (nb,r), then reduce over quad dim (2 stages)
            float t1 = 0.f, t2 = 0.f;
            #pragma unroll
            for (int nb = 0; nb < 8; nb++)
                #pragma unroll
                for (int r = 0; r < 4; r++) {
                    float z = fmaxf(acc[nb][r] + bwp_r[nb][r], 0.f);
                    t1 += z; t2 = fmaf(z, z, t2);
                }
            t1 += __shfl_xor(t1, 16); t2 += __shfl_xor(t2, 16);
            t1 += __shfl_xor(t1, 32); t2 += __shfl_xor(t2, 32);
            float mu2 = t1 * (1.f / 128.f);
            float rs2 = rsqrtf(t2 * (1.f / 128.f) - mu2 * mu2 + 1e-5f);
            if (base + m >= re) rs2 = 0.f;   // mask pad edge (this lane's edge = m)
            V = fmaf(rs2, mu2, V);
            #pragma unroll
            for (int nb = 0; nb < 8; nb++)
                #pragma unroll
                for (int r = 0; r < 4; r++) {
                    float z = fmaxf(acc[nb][r] + bwp_r[nb][r], 0.f);
                    hacc[nb][r] = fmaf(rs2, z, hacc[nb][r]);
                }
        }
        // transpose-reduce hacc over the 16 edge-lanes (4 stages, static indices)
        bool sel0 = (m & 1), sel1 = (m & 2), sel2 = (m & 4), sel3 = (m & 8);
        float s16v[16];
        #pragma unroll
        for (int k = 0; k < 16; k++) {            // k = nb*2 + (r>>1)
            int nb = k >> 1, rh = (k & 1) << 1;
            float a = hacc[nb][rh], b = hacc[nb][rh + 1];
            float keep = sel0 ? b : a;
            float send = sel0 ? a : b;
            s16v[k] = keep + __shfl_xor(send, 1);
        }
        float s8v[8];
        #pragma unroll
        for (int nb = 0; nb < 8; nb++) {
            float a = s16v[nb * 2], b = s16v[nb * 2 + 1];
            float keep = sel1 ? b : a;
            float send = sel1 ? a : b;
            s8v[nb] = keep + __shfl_xor(send, 2);
        }
        float s4v[4];
        #pragma unroll
        for (int k = 0; k < 4; k++) {             // k = nb>>1
            float a = s8v[k * 2], b = s8v[k * 2 + 1];
            float keep = sel2 ? b : a;
            float send = sel2 ? a : b;
            s4v[k] = keep + __shfl_xor(send, 4);
        }
        float s2v[2];
        #pragma unroll
        for (int k = 0; k < 2; k++) {             // k = nb bit2
            float a = s4v[k * 2], b = s4v[k * 2 + 1];
            float keep = sel3 ? b : a;
            float send = sel3 ? a : b;
            s2v[k] = keep + __shfl_xor(send, 8);
        }
        V += __shfl_xor(V, 1); V += __shfl_xor(V, 2);
        V += __shfl_xor(V, 4); V += __shfl_xor(V, 8);
        float dg = (float)(re - rs);
        #pragma unroll
        for (int k = 0; k < 2; k++) {
            int nb = (k << 2) | (((m >> 3) & 1) << 1) | ((m >> 2) & 1);
            int f = nb * 16 + q * 4 + (m & 3);
            float gg = ldf(lng, f, fl), bb = ldf(lnb, f, fl);
            h1[(size_t)node * 128 + f] = f2bf(fmaf(gg, s2v[k] - V, dg * bb));
        }
    }
}

// ---------------- fused q/k/v/skip projection GEMM (bf16 h input) ----------------
__global__ __launch_bounds__(256) void k_proj(
    const u16* __restrict__ hin, const u16* __restrict__ wt,
    const float* __restrict__ bcat, u16* __restrict__ outp)
{
    __shared__ u16 sA[64 * 136];
    __shared__ u16 sB[128 * 136];
    int t = threadIdx.x;
    int l = t & 63, w = t >> 6;
    int m = l & 15, q = l >> 4;
    int rowbase = blockIdx.x * 64;
    for (int c = t; c < 64 * 32; c += 256) {
        int row = c >> 5, ch = c & 31;
        int gr = rowbase + row;
        ushort4 pk = make_ushort4(0, 0, 0, 0);
        if (gr < N_NODES) pk = *(const ushort4*)&hin[(size_t)gr * 128 + ch * 4];
        *(ushort4*)&sA[row * 136 + ch * 4] = pk;
    }
    __syncthreads();
    bf16x8 afrag[4];
    #pragma unroll
    for (int kb = 0; kb < 4; kb++)
        afrag[kb] = *(const bf16x8*)&sA[(w * 16 + m) * 136 + kb * 32 + q * 8];

    f32x4 zf = {0.f, 0.f, 0.f, 0.f};
    for (int g = 0; g < 4; ++g) {
        __syncthreads();
        for (int c = t; c < 128 * 32; c += 256) {
            int row = c >> 5, ch = c & 31;
            *(ushort4*)&sB[row * 136 + ch * 4] = *(const ushort4*)&wt[(g * 128 + row) * 128 + ch * 4];
        }
        __syncthreads();
        f32x4 acc[8];
        #pragma unroll
        for (int nb = 0; nb < 8; nb++) acc[nb] = zf;
        #pragma unroll
        for (int nb = 0; nb < 8; nb++) {
            const u16* brow = &sB[(nb * 16 + m) * 136 + q * 8];
            #pragma unroll
            for (int kb = 0; kb < 4; kb++) {
                bf16x8 bfrag = *(const bf16x8*)(brow + kb * 32);
                acc[nb] = __builtin_amdgcn_mfma_f32_16x16x32_bf16(afrag[kb], bfrag, acc[nb], 0, 0, 0);
            }
        }
        #pragma unroll
        for (int nb = 0; nb < 8; nb++) {
            int col = g * 128 + nb * 16 + m;
            float bb = bcat[col];
            #pragma unroll
            for (int r = 0; r < 4; r++) {
                int row = rowbase + w * 16 + q * 4 + r;
                if (row < N_NODES) outp[(size_t)row * 512 + col] = f2bf(acc[nb][r] + bb);
            }
        }
    }
}

// ---------------- attention: wave per dst node, 4 edge-slots x 16 lanes, prefetched ----------------
__global__ __launch_bounds__(256) void k_attn(
    const u16* __restrict__ qkvs,
    const int* __restrict__ rowst, const int2* __restrict__ csr,
    const void* __restrict__ wep, u16* __restrict__ hout,
    const int* __restrict__ flag)
{
    int fl = getflag(flag);
    int t = threadIdx.x;
    int l = t & 63, w = t >> 6;
    int dstn = blockIdx.x * 4 + w;        // grid*4 == N exactly
    int lane16 = l & 15, sub = l >> 4;
    int f0 = lane16 * 8;                  // 8 features per lane
    const float scale = 0.17677669529663687f;  // 1/sqrt(32)

    bf16x8 q8 = *(const bf16x8*)&qkvs[(size_t)dstn * 512 + f0];
    float qf[8], wef[8];
    #pragma unroll
    for (int j = 0; j < 8; j++) {
        qf[j] = bf2f((u16)q8[j]) * scale;
        wef[j] = ldf(wep, f0 + j, fl);
    }
    float mi = -1e30f, si = 0.f;
    float a8[8];
    #pragma unroll
    for (int j = 0; j < 8; j++) a8[j] = 0.f;

    int rs = rowst[dstn], re = rowst[dstn + 1];
    int i = rs + sub;
    int2 sa;
    bf16x8 k8, v8;
    if (i < re) {
        sa = csr[i];
        const u16* sr = &qkvs[(size_t)sa.x * 512 + f0];
        k8 = *(const bf16x8*)(sr + 128);
        v8 = *(const bf16x8*)(sr + 256);
    }
    for (; i < re; i += 4) {
        float av = __int_as_float(sa.y);
        float p = 0.f;
        float ve[8];
        #pragma unroll
        for (int j = 0; j < 8; j++) {
            float kv = fmaf(av, wef[j], bf2f((u16)k8[j]));
            p = fmaf(qf[j], kv, p);
            ve[j] = fmaf(av, wef[j], bf2f((u16)v8[j]));
        }
        if (i + 4 < re) {
            sa = csr[i + 4];
            const u16* sr = &qkvs[(size_t)sa.x * 512 + f0];
            k8 = *(const bf16x8*)(sr + 128);
            v8 = *(const bf16x8*)(sr + 256);
        }
        p += __shfl_xor(p, 1); p += __shfl_xor(p, 2);   // sum over head's 4 lanes
        float mn = fmaxf(mi, p);
        float fs = __expf(mi - mn);
        float pe = __expf(p - mn);
        si = fmaf(si, fs, pe);
        #pragma unroll
        for (int j = 0; j < 8; j++) a8[j] = fmaf(a8[j], fs, pe * ve[j]);
        mi = mn;
    }
    #pragma unroll
    for (int off = 16; off < 64; off <<= 1) {
        float mo = __shfl_xor(mi, off);
        float so = __shfl_xor(si, off);
        float mm = fmaxf(mi, mo);
        float f1 = __expf(mi - mm);
        float f2 = __expf(mo - mm);
        si = si * f1 + so * f2;
        #pragma unroll
        for (int j = 0; j < 8; j++) {
            float ao = __shfl_xor(a8[j], off);
            a8[j] = a8[j] * f1 + ao * f2;
        }
        mi = mm;
    }
    if (sub == 0) {
        float inv = 1.f / (si + 1e-16f);
        bf16x8 s8 = *(const bf16x8*)&qkvs[(size_t)dstn * 512 + 384 + f0];
        ushort4 p0, p1;
        float o[8];
        #pragma unroll
        for (int j = 0; j < 8; j++)
            o[j] = fmaxf(fmaf(a8[j], inv, bf2f((u16)s8[j])), 0.f);
        p0.x = f2bf(o[0]); p0.y = f2bf(o[1]); p0.z = f2bf(o[2]); p0.w = f2bf(o[3]);
        p1.x = f2bf(o[4]); p1.y = f2bf(o[5]); p1.z = f2bf(o[6]); p1.w = f2bf(o[7]);
        u16* hr = hout + (size_t)dstn * 128 + f0;
        *(ushort4*)hr = p0;
        *(ushort4*)(hr + 4) = p1;
    }
}

// ---------------- global mean pool (bf16 h input) ----------------
__global__ __launch_bounds__(256) void k_pool(
    const u16* __restrict__ h, const int* __restrict__ batch,
    float* __restrict__ gsum, float* __restrict__ gcnt)
{
    __shared__ float ssum[8 * 128];
    __shared__ float scnt[8];
    int t = threadIdx.x;
    for (int i = t; i < 8 * 128; i += 256) ssum[i] = 0.f;
    if (t < 8) scnt[t] = 0.f;
    __syncthreads();
    int f = t & 127, half = t >> 7;
    int per = (N_NODES + gridDim.x - 1) / gridDim.x;
    int lo = blockIdx.x * per;
    int hi = lo + per; if (hi > N_NODES) hi = N_NODES;
    float racc = 0.f; float rcnt = 0.f; int rg = -1;
    for (int n = lo + half; n < hi; n += 2) {
        int g = batch[n];
        if (g != rg) {
            if (rg >= 0) { atomicAdd(&ssum[rg * 128 + f], racc); if (f == 0) atomicAdd(&scnt[rg], rcnt); }
            rg = g; racc = 0.f; rcnt = 0.f;
        }
        racc += bf2f(h[(size_t)n * 128 + f]);
        rcnt += 1.f;
    }
    if (rg >= 0) { atomicAdd(&ssum[rg * 128 + f], racc); if (f == 0) atomicAdd(&scnt[rg], rcnt); }
    __syncthreads();
    for (int i = t; i < 8 * 128; i += 256) unsafeAtomicAdd(&gsum[i], ssum[i]);
    if (t < 8) unsafeAtomicAdd(&gcnt[t], scnt[t]);
}

__global__ void k_out(const float* __restrict__ gsum, const float* __restrict__ gcnt,
                      void* __restrict__ outp, const int* __restrict__ flag) {
    int fl = getflag(flag);
    int t = threadIdx.x;  // 1024
    float c = fmaxf(gcnt[t >> 7], 1.f);
    float v = gsum[t] / c;
    if (fl) ((float*)outp)[t] = v;
    else ((u16*)outp)[t] = f2bf(v);
}

extern "C" void kernel_launch(void* const* d_in, const int* in_sizes, int n_in,
                              void* d_out, int out_size, void* d_ws, size_t ws_size,
                              hipStream_t stream)
{
    (void)in_sizes; (void)n_in; (void)out_size; (void)ws_size;
    const void* x    = d_in[0];
    const int* ei    = (const int*)d_in[1];
    const void* ea   = d_in[2];
    const int* batch = (const int*)d_in[3];
    const void* w1   = d_in[4];
    const void* b1   = d_in[5];
    const void* lng  = d_in[6];
    const void* lnb  = d_in[7];
    const void* w2   = d_in[8];
    const void* b2   = d_in[9];
    const int* srcp = ei;
    const int* dstp = ei + N_EDGES;

    char* wsb = (char*)d_ws;
    size_t cur = 0;
    auto alloc = [&](size_t sz) -> void* {
        void* p = wsb + cur;
        cur += (sz + 255) & ~(size_t)255;
        return p;
    };
    u16*   y      = (u16*)  alloc((size_t)N_NODES * 128 * 2);   // bf16 lin1 output
    u16*   h1     = (u16*)  alloc((size_t)N_NODES * 128 * 2);   // bf16; reused as h3
    u16*   h2     = (u16*)  alloc((size_t)N_NODES * 128 * 2);   // bf16
    u16*   qkvs   = (u16*)  alloc((size_t)N_NODES * 512 * 2);
    int2*  csr    = (int2*) alloc((size_t)N_EDGES * 8);
    u16*   gt     = (u16*)  alloc(128 * 128 * 2);
    u16*   wcat1  = (u16*)  alloc(512 * 128 * 2);
    u16*   wcat2  = (u16*)  alloc(512 * 128 * 2);
    float* bwp    = (float*)alloc(128 * 4);
    u32*   w1pk   = (u32*)  alloc(64 * 4);
    float* bcat1  = (float*)alloc(512 * 4);
    float* bcat2  = (float*)alloc(512 * 4);
    int*   cntdeg = (int*)  alloc((size_t)N_NODES * 4);
    int*   rowst  = (int*)  alloc((size_t)(N_NODES + 1) * 4);
    int*   nxt    = (int*)  alloc((size_t)N_NODES * 4);
    float* gsum   = (float*)alloc((8 * 128 + 8) * 4);
    int*   dtflag = (int*)  alloc(256);
    u16*   h3 = h1;   // h1 is dead after first k_proj

    hipMemsetAsync(cntdeg, 0, (size_t)N_NODES * 4, stream);
    hipMemsetAsync(gsum, 0, (8 * 128 + 8) * 4, stream);

    k_detect<<<1, 256, 0, stream>>>((const u16*)x, dtflag);

    P8 pw; P8 pb;
    pw.s[0] = d_in[10]; pw.s[1] = d_in[12]; pw.s[2] = d_in[14]; pw.s[3] = d_in[17];
    pw.s[4] = d_in[19]; pw.s[5] = d_in[21]; pw.s[6] = d_in[23]; pw.s[7] = d_in[26];
    pb.s[0] = d_in[11]; pb.s[1] = d_in[13]; pb.s[2] = d_in[15]; pb.s[3] = d_in[18];
    pb.s[4] = d_in[20]; pb.s[5] = d_in[22]; pb.s[6] = d_in[24]; pb.s[7] = d_in[27];
    k_transpose8<<<512, 256, 0, stream>>>(pw, wcat1, wcat2, dtflag);
    k_bcat8<<<4, 256, 0, stream>>>(pb, bcat1, bcat2, dtflag);
    k_prep_w2<<<1, 128, 0, stream>>>(w2, lng, lnb, b2, w1, gt, bwp, w1pk, dtflag);

    k_embed_lin1<<<782, 256, 0, stream>>>(x, w1, b1, y, dtflag);
    k_degree<<<3125, 256, 0, stream>>>(dstp, cntdeg);
    k_scan<<<1, 1024, 0, stream>>>(cntdeg, rowst, nxt);
    k_scatter<<<3125, 256, 0, stream>>>(dstp, srcp, ea, nxt, csr, dtflag);
    k_embed_edges<<<2048, 256, 0, stream>>>(y, csr, rowst, lng, lnb,
                                            gt, w1pk, bwp, h1, dtflag);
    k_proj<<<782, 256, 0, stream>>>(h1, wcat1, bcat1, qkvs);
    k_attn<<<12500, 256, 0, stream>>>(qkvs, rowst, csr, d_in[16], h2, dtflag);
    k_proj<<<782, 256, 0, stream>>>(h2, wcat2, bcat2, qkvs);
    k_attn<<<12500, 256, 0, stream>>>(qkvs, rowst, csr, d_in[25], h3, dtflag);
    k_pool<<<128, 256, 0, stream>>>(h3, batch, gsum, gsum + 8 * 128);
    k_out<<<1, 1024, 0, stream>>>(gsum, gsum + 8 * 128, d_out, dtflag);
}

// Round 9
// 928.857 us; speedup vs baseline: 1.7302x; 1.0348x over previous
//
#include <hip/hip_runtime.h>

typedef unsigned short u16;
typedef unsigned int u32;
typedef __attribute__((ext_vector_type(8))) short bf16x8;
typedef __attribute__((ext_vector_type(4))) float f32x4;

#define N_NODES 50000
#define N_EDGES 800000

__device__ __forceinline__ float bf2f(u16 u) {
    union { u32 i; float f; } v; v.i = ((u32)u) << 16; return v.f;
}
__device__ __forceinline__ u16 f2bf(float f) {
    union { u32 i; float f; } v; v.f = f;
    u32 i = v.i;
    return (u16)((i + 0x7FFFu + ((i >> 16) & 1u)) >> 16);
}
// dtype-agnostic load: fl!=0 -> float32 buffer, else bf16 (u16) buffer
__device__ __forceinline__ float ldf(const void* p, int i, int fl) {
    return fl ? ((const float*)p)[i] : bf2f(((const u16*)p)[i]);
}
__device__ __forceinline__ int getflag(const int* flag) {
    return __builtin_amdgcn_readfirstlane(*flag);
}

// ---------------- dtype detection ----------------
__global__ void k_detect(const u16* __restrict__ xr, int* __restrict__ flag) {
    __shared__ int sc[256];
    int t = threadIdx.x;
    int c = 0;
    for (int i = t; i < 4096; i += 256) {
        u32 e = (xr[i] >> 7) & 0xFF;
        if (e >= 143) c++;
    }
    sc[t] = c;
    __syncthreads();
    for (int s = 128; s > 0; s >>= 1) {
        if (t < s) sc[t] += sc[t + s];
        __syncthreads();
    }
    if (t == 0) *flag = (sc[0] > 64) ? 1 : 0;   // 1 = float32, 0 = bf16
}

// ---------------- weight prep ----------------
struct P8 { const void* s[8]; };

__global__ void k_transpose8(P8 p, u16* __restrict__ dst0, u16* __restrict__ dst1,
                             const int* __restrict__ flag) {
    int fl = getflag(flag);
    int gid = blockIdx.x * 256 + threadIdx.x;   // 512 blocks -> 8 * 16384
    int wi = gid >> 14;
    int id = gid & 16383;
    int k = id >> 7, n = id & 127;
    u16* d = (wi < 4) ? (dst0 + wi * 16384) : (dst1 + (wi - 4) * 16384);
    d[n * 128 + k] = f2bf(ldf(p.s[wi], id, fl));
}

__global__ void k_bcat8(P8 p, float* __restrict__ out1, float* __restrict__ out2,
                        const int* __restrict__ flag) {
    int fl = getflag(flag);
    int t = blockIdx.x * 256 + threadIdx.x;   // 4 blocks -> 1024
    float v = ldf(p.s[t >> 7], t & 127, fl);
    if (t < 512) out1[t] = v; else out2[t - 512] = v;
}

// G = diag(lng)*W2 folded; csum[n] = sum_f G[f,n]; bwp[n] = sum_f lnb_f*W2[f,n] + b2[n]
// also packs the W1 edge row (row 64) as bf16 pairs into w1pk[64]
__global__ void k_prep_w2(const void* __restrict__ w2, const void* __restrict__ lng_,
                          const void* __restrict__ lnb_, const void* __restrict__ b2_,
                          const void* __restrict__ w1, u16* __restrict__ gt,
                          float* __restrict__ csum, float* __restrict__ bwp,
                          u32* __restrict__ w1pk, const int* __restrict__ flag)
{
    int fl = getflag(flag);
    int t = threadIdx.x;   // 128 threads, 1 block; t = output column n
    if (t < 128) {
        float cs = 0.f, bw = 0.f;
        for (int f = 0; f < 128; f++) {
            float wv = ldf(w2, f * 128 + t, fl);
            float g = ldf(lng_, f, fl);
            float b = ldf(lnb_, f, fl);
            u16 gwq = f2bf(g * wv);
            gt[t * 128 + f] = gwq;
            cs += bf2f(gwq);
            bw = fmaf(b, wv, bw);
        }
        csum[t] = cs;
        bwp[t] = bw + ldf(b2_, t, fl);
        if (t < 64)
            w1pk[t] = (u32)f2bf(ldf(w1, 64 * 128 + t * 2, fl)) |
                      ((u32)f2bf(ldf(w1, 64 * 128 + t * 2 + 1, fl)) << 16);
    }
}

// ---------------- embed: node-side lin1  y = x @ W1[:64] + b1  (bf16 out) ----------------
__global__ __launch_bounds__(256) void k_embed_lin1(
    const void* __restrict__ x, const void* __restrict__ w1,
    const void* __restrict__ b1, u16* __restrict__ y,
    const int* __restrict__ flag)
{
    __shared__ float sx[2][64];
    int fl = getflag(flag);
    int t = threadIdx.x;
    int col = t & 127, half = t >> 7;
    float wreg[64];
    #pragma unroll
    for (int k = 0; k < 64; k++) wreg[k] = ldf(w1, k * 128 + col, fl);
    float bias = ldf(b1, col, fl);
    int base = blockIdx.x * 64;
    for (int it = 0; it < 32; ++it) {
        __syncthreads();
        if (t < 128) {
            int nh = base + it * 2 + (t >> 6);
            sx[t >> 6][t & 63] = (nh < N_NODES) ? ldf(x, nh * 64 + (t & 63), fl) : 0.f;
        }
        __syncthreads();
        float acc = bias;
        #pragma unroll
        for (int k = 0; k < 64; k++) acc = fmaf(sx[half][k], wreg[k], acc);
        int n = base + it * 2 + half;
        if (n < N_NODES) y[(size_t)n * 128 + col] = f2bf(acc);
    }
}

// ---------------- CSR build ----------------
__global__ void k_degree(const int* __restrict__ dst, int* __restrict__ cnt) {
    int e = blockIdx.x * 256 + threadIdx.x;
    if (e < N_EDGES) atomicAdd(&cnt[dst[e]], 1);
}

__global__ __launch_bounds__(1024) void k_scan(const int* __restrict__ cnt,
                                               int* __restrict__ row_start,
                                               int* __restrict__ nxt)
{
    __shared__ int wsum[16];
    __shared__ int s_tot;
    int t = threadIdx.x, lane = t & 63, wid = t >> 6;
    int run = 0;
    for (int base = 0; base < N_NODES; base += 8192) {
        int i0 = base + t * 8;
        int v[8], pre[8];
        int s = 0;
        #pragma unroll
        for (int j = 0; j < 8; j++) {
            int i = i0 + j;
            v[j] = (i < N_NODES) ? cnt[i] : 0;
            pre[j] = s;
            s += v[j];
        }
        int tsum = s;
        int sc = tsum;
        #pragma unroll
        for (int off = 1; off < 64; off <<= 1) {
            int o = __shfl_up(sc, off);
            if (lane >= off) sc += o;
        }
        if (lane == 63) wsum[wid] = sc;
        __syncthreads();
        if (t == 0) {
            int acc2 = 0;
            #pragma unroll
            for (int k2 = 0; k2 < 16; k2++) { int vv = wsum[k2]; wsum[k2] = acc2; acc2 += vv; }
            s_tot = acc2;
        }
        __syncthreads();
        int texcl = run + wsum[wid] + (sc - tsum);
        #pragma unroll
        for (int j = 0; j < 8; j++) {
            int i = i0 + j;
            if (i < N_NODES) { int ex = texcl + pre[j]; row_start[i] = ex; nxt[i] = ex; }
        }
        run += s_tot;
        __syncthreads();
    }
    if (t == 0) row_start[N_NODES] = run;
}

// scatter edges into CSR order carrying (src, edge_attr) payload
__global__ void k_scatter(const int* __restrict__ dst, const int* __restrict__ srcp,
                          const void* __restrict__ ea, int* __restrict__ nxt,
                          int2* __restrict__ csr, const int* __restrict__ flag) {
    int fl = getflag(flag);
    int e = blockIdx.x * 256 + threadIdx.x;
    if (e < N_EDGES) {
        int p = atomicAdd(&nxt[dst[e]], 1);
        int2 v;
        v.x = srcp[e];
        v.y = __float_as_int(ldf(ea, e, fl));
        csr[p] = v;
    }
}

// ---------------- embed: wave-per-node, G^T as MFMA A, edges as B ----------------
// LN1 applied via linearity AFTER the MFMA: G@norm(u) = rsd*(G@u) - mu*rsd*csum,
// so relu(u) is packed ONCE (no vv array, no normalize pass). csum/bwp held as
// bf16-packed pairs. Next-chunk csr+y prefetched under MFMA+epilogue.
__global__ __launch_bounds__(256) void k_embed_edges(
    const u16* __restrict__ y, const int2* __restrict__ csr,
    const int* __restrict__ rowst,
    const void* __restrict__ lng, const void* __restrict__ lnb,
    const u16* __restrict__ gt, const u32* __restrict__ w1pk,
    const float* __restrict__ csum, const float* __restrict__ bwp,
    u16* __restrict__ h1, const int* __restrict__ flag)
{
    __shared__ u16 sB[128 * 136];   // G^T rows (f_out), padded (2-way conflict = free)
    __shared__ u32 sW1[64];         // packed bf16 pairs of W1 edge row
    int fl = getflag(flag);
    int t = threadIdx.x;
    for (int c = t; c < 128 * 32; c += 256) {
        int row = c >> 5, ch = c & 31;
        *(ushort4*)&sB[row * 136 + ch * 4] = *(const ushort4*)&gt[row * 128 + ch * 4];
    }
    if (t < 64) sW1[t] = w1pk[t];
    int l = t & 63, w = t >> 6;
    int m = l & 15, q = l >> 4;

    // packed bf16 (csum,bwp) pairs at f_out = nb*16 + q*4 + rh*2 (+0,+1)
    u32 csum_pk[16], bwp_pk[16];
    #pragma unroll
    for (int nb = 0; nb < 8; nb++)
        #pragma unroll
        for (int rh = 0; rh < 2; rh++) {
            int f = nb * 16 + q * 4 + rh * 2;
            csum_pk[nb * 2 + rh] = (u32)f2bf(csum[f]) | ((u32)f2bf(csum[f + 1]) << 16);
            bwp_pk[nb * 2 + rh]  = (u32)f2bf(bwp[f])  | ((u32)f2bf(bwp[f + 1])  << 16);
        }
    __syncthreads();

    f32x4 zf = {0.f, 0.f, 0.f, 0.f};
    int stride = gridDim.x * 4;
    for (int node = blockIdx.x * 4 + w; node < N_NODES; node += stride) {
        int rs = rowst[node], re = rowst[node + 1];
        float hacc[8][4];
        #pragma unroll
        for (int nb = 0; nb < 8; nb++)
            #pragma unroll
            for (int r = 0; r < 4; r++) hacc[nb][r] = 0.f;
        float V = 0.f;
        if (rs < re) {
            // pipeline prologue
            int idx = rs + m;
            int2 sa = csr[(idx < re) ? idx : (re - 1)];
            bf16x8 yv[4];
            {
                const u16* yr = y + (size_t)sa.x * 128 + q * 8;
                #pragma unroll
                for (int kb = 0; kb < 4; kb++) yv[kb] = *(const bf16x8*)(yr + kb * 32);
            }
            for (int base = rs; base < re; base += 16) {
                float av = __int_as_float(sa.y);
                // single pass: u = relu(y + av*w1), stats, pack
                bf16x8 efrag[4];
                float s1 = 0.f, s2 = 0.f;
                #pragma unroll
                for (int kb = 0; kb < 4; kb++) {
                    const u32* wr = &sW1[kb * 16 + q * 4];
                    #pragma unroll
                    for (int j = 0; j < 8; j++) {
                        float wv = bf2f((u16)((wr[j >> 1] >> ((j & 1) * 16)) & 0xffff));
                        float u = fmaxf(fmaf(av, wv, bf2f((u16)yv[kb][j])), 0.f);
                        s1 += u; s2 = fmaf(u, u, s2);
                        efrag[kb][j] = (short)f2bf(u);
                    }
                }
                // prefetch next chunk (csr + y rows) under MFMA+epilogue
                int nbase = base + 16;
                if (nbase < re) {
                    int ni = nbase + m;
                    sa = csr[(ni < re) ? ni : (re - 1)];
                    const u16* yr = y + (size_t)sa.x * 128 + q * 8;
                    #pragma unroll
                    for (int kb = 0; kb < 4; kb++) yv[kb] = *(const bf16x8*)(yr + kb * 32);
                }
                // LN1 stats over f_in (quad dim)
                s1 += __shfl_xor(s1, 16); s2 += __shfl_xor(s2, 16);
                s1 += __shfl_xor(s1, 32); s2 += __shfl_xor(s2, 32);
                float mu = s1 * (1.f / 128.f);
                float alpha = rsqrtf(s2 * (1.f / 128.f) - mu * mu + 1e-5f);
                float beta = -mu * alpha;

                f32x4 acc[8];
                #pragma unroll
                for (int nb = 0; nb < 8; nb++) acc[nb] = zf;
                #pragma unroll
                for (int nb = 0; nb < 8; nb++) {
                    const u16* grow = &sB[(nb * 16 + m) * 136 + q * 8];
                    #pragma unroll
                    for (int kb = 0; kb < 4; kb++) {
                        bf16x8 gfrag = *(const bf16x8*)(grow + kb * 32);
                        acc[nb] = __builtin_amdgcn_mfma_f32_16x16x32_bf16(gfrag, efrag[kb], acc[nb], 0, 0, 0);
                    }
                }
                // LN2 stats: z = relu(alpha*acc + beta*csum + bwp), reduce over quads
                float t1 = 0.f, t2 = 0.f;
                #pragma unroll
                for (int nb = 0; nb < 8; nb++)
                    #pragma unroll
                    for (int r = 0; r < 4; r++) {
                        u32 cp = csum_pk[nb * 2 + (r >> 1)];
                        u32 bp = bwp_pk[nb * 2 + (r >> 1)];
                        float cs = bf2f((u16)((r & 1) ? (cp >> 16) : (cp & 0xffff)));
                        float bw = bf2f((u16)((r & 1) ? (bp >> 16) : (bp & 0xffff)));
                        float z = fmaxf(fmaf(alpha, acc[nb][r], fmaf(beta, cs, bw)), 0.f);
                        t1 += z; t2 = fmaf(z, z, t2);
                    }
                t1 += __shfl_xor(t1, 16); t2 += __shfl_xor(t2, 16);
                t1 += __shfl_xor(t1, 32); t2 += __shfl_xor(t2, 32);
                float mu2 = t1 * (1.f / 128.f);
                float rs2 = rsqrtf(t2 * (1.f / 128.f) - mu2 * mu2 + 1e-5f);
                if (base + m >= re) rs2 = 0.f;   // mask pad edge (lane's edge = m)
                V = fmaf(rs2, mu2, V);
                #pragma unroll
                for (int nb = 0; nb < 8; nb++)
                    #pragma unroll
                    for (int r = 0; r < 4; r++) {
                        u32 cp = csum_pk[nb * 2 + (r >> 1)];
                        u32 bp = bwp_pk[nb * 2 + (r >> 1)];
                        float cs = bf2f((u16)((r & 1) ? (cp >> 16) : (cp & 0xffff)));
                        float bw = bf2f((u16)((r & 1) ? (bp >> 16) : (bp & 0xffff)));
                        float z = fmaxf(fmaf(alpha, acc[nb][r], fmaf(beta, cs, bw)), 0.f);
                        hacc[nb][r] = fmaf(rs2, z, hacc[nb][r]);
                    }
            }
        }
        // transpose-reduce hacc over the 16 edge-lanes (4 stages, static indices)
        bool sel0 = (m & 1), sel1 = (m & 2), sel2 = (m & 4), sel3 = (m & 8);
        float s16v[16];
        #pragma unroll
        for (int k = 0; k < 16; k++) {            // k = nb*2 + (r>>1)
            int nb = k >> 1, rh = (k & 1) << 1;
            float a = hacc[nb][rh], b = hacc[nb][rh + 1];
            float keep = sel0 ? b : a;
            float send = sel0 ? a : b;
            s16v[k] = keep + __shfl_xor(send, 1);
        }
        float s8v[8];
        #pragma unroll
        for (int nb = 0; nb < 8; nb++) {
            float a = s16v[nb * 2], b = s16v[nb * 2 + 1];
            float keep = sel1 ? b : a;
            float send = sel1 ? a : b;
            s8v[nb] = keep + __shfl_xor(send, 2);
        }
        float s4v[4];
        #pragma unroll
        for (int k = 0; k < 4; k++) {
            float a = s8v[k * 2], b = s8v[k * 2 + 1];
            float keep = sel2 ? b : a;
            float send = sel2 ? a : b;
            s4v[k] = keep + __shfl_xor(send, 4);
        }
        float s2v[2];
        #pragma unroll
        for (int k = 0; k < 2; k++) {
            float a = s4v[k * 2], b = s4v[k * 2 + 1];
            float keep = sel3 ? b : a;
            float send = sel3 ? a : b;
            s2v[k] = keep + __shfl_xor(send, 8);
        }
        V += __shfl_xor(V, 1); V += __shfl_xor(V, 2);
        V += __shfl_xor(V, 4); V += __shfl_xor(V, 8);
        float dg = (float)(re - rs);
        #pragma unroll
        for (int k = 0; k < 2; k++) {
            int nb = (k << 2) | (((m >> 3) & 1) << 1) | ((m >> 2) & 1);
            int f = nb * 16 + q * 4 + (m & 3);
            float gg = ldf(lng, f, fl), bb = ldf(lnb, f, fl);
            h1[(size_t)node * 128 + f] = f2bf(fmaf(gg, s2v[k] - V, dg * bb));
        }
    }
}

// ---------------- fused q/k/v/skip projection GEMM (bf16 h input) ----------------
__global__ __launch_bounds__(256) void k_proj(
    const u16* __restrict__ hin, const u16* __restrict__ wt,
    const float* __restrict__ bcat, u16* __restrict__ outp)
{
    __shared__ u16 sA[64 * 136];
    __shared__ u16 sB[128 * 136];
    int t = threadIdx.x;
    int l = t & 63, w = t >> 6;
    int m = l & 15, q = l >> 4;
    int rowbase = blockIdx.x * 64;
    for (int c = t; c < 64 * 32; c += 256) {
        int row = c >> 5, ch = c & 31;
        int gr = rowbase + row;
        ushort4 pk = make_ushort4(0, 0, 0, 0);
        if (gr < N_NODES) pk = *(const ushort4*)&hin[(size_t)gr * 128 + ch * 4];
        *(ushort4*)&sA[row * 136 + ch * 4] = pk;
    }
    __syncthreads();
    bf16x8 afrag[4];
    #pragma unroll
    for (int kb = 0; kb < 4; kb++)
        afrag[kb] = *(const bf16x8*)&sA[(w * 16 + m) * 136 + kb * 32 + q * 8];

    f32x4 zf = {0.f, 0.f, 0.f, 0.f};
    for (int g = 0; g < 4; ++g) {
        __syncthreads();
        for (int c = t; c < 128 * 32; c += 256) {
            int row = c >> 5, ch = c & 31;
            *(ushort4*)&sB[row * 136 + ch * 4] = *(const ushort4*)&wt[(g * 128 + row) * 128 + ch * 4];
        }
        __syncthreads();
        f32x4 acc[8];
        #pragma unroll
        for (int nb = 0; nb < 8; nb++) acc[nb] = zf;
        #pragma unroll
        for (int nb = 0; nb < 8; nb++) {
            const u16* brow = &sB[(nb * 16 + m) * 136 + q * 8];
            #pragma unroll
            for (int kb = 0; kb < 4; kb++) {
                bf16x8 bfrag = *(const bf16x8*)(brow + kb * 32);
                acc[nb] = __builtin_amdgcn_mfma_f32_16x16x32_bf16(afrag[kb], bfrag, acc[nb], 0, 0, 0);
            }
        }
        #pragma unroll
        for (int nb = 0; nb < 8; nb++) {
            int col = g * 128 + nb * 16 + m;
            float bb = bcat[col];
            #pragma unroll
            for (int r = 0; r < 4; r++) {
                int row = rowbase + w * 16 + q * 4 + r;
                if (row < N_NODES) outp[(size_t)row * 512 + col] = f2bf(acc[nb][r] + bb);
            }
        }
    }
}

// ---------------- attention: wave per dst node, 4 subs x 16 lanes, edge-pair ILP2 ----------------
__global__ __launch_bounds__(256) void k_attn(
    const u16* __restrict__ qkvs,
    const int* __restrict__ rowst, const int2* __restrict__ csr,
    const void* __restrict__ wep, u16* __restrict__ hout,
    const int* __restrict__ flag)
{
    int fl = getflag(flag);
    int t = threadIdx.x;
    int l = t & 63, w = t >> 6;
    int dstn = blockIdx.x * 4 + w;        // grid*4 == N exactly
    int lane16 = l & 15, sub = l >> 4;
    int f0 = lane16 * 8;                  // 8 features per lane
    const float scale = 0.17677669529663687f;  // 1/sqrt(32)

    bf16x8 q8 = *(const bf16x8*)&qkvs[(size_t)dstn * 512 + f0];
    float qf[8], wef[8];
    #pragma unroll
    for (int j = 0; j < 8; j++) {
        qf[j] = bf2f((u16)q8[j]) * scale;
        wef[j] = ldf(wep, f0 + j, fl);
    }
    float mi = -1e30f, si = 0.f;
    float a8[8];
    #pragma unroll
    for (int j = 0; j < 8; j++) a8[j] = 0.f;

    int rs = rowst[dstn], re = rowst[dstn + 1];
    int i = rs + sub;
    // paired iterations: edges i and i+4, stride 8 (2 loads in flight, 1 merge)
    for (; i + 4 < re; i += 8) {
        int2 sa = csr[i];
        int2 sb = csr[i + 4];
        float ava = __int_as_float(sa.y);
        float avb = __int_as_float(sb.y);
        const u16* sra = &qkvs[(size_t)sa.x * 512 + f0];
        const u16* srb = &qkvs[(size_t)sb.x * 512 + f0];
        bf16x8 k8a = *(const bf16x8*)(sra + 128);
        bf16x8 v8a = *(const bf16x8*)(sra + 256);
        bf16x8 k8b = *(const bf16x8*)(srb + 128);
        bf16x8 v8b = *(const bf16x8*)(srb + 256);
        float pa = 0.f, pb = 0.f;
        float vea[8], veb[8];
        #pragma unroll
        for (int j = 0; j < 8; j++) {
            pa = fmaf(qf[j], fmaf(ava, wef[j], bf2f((u16)k8a[j])), pa);
            pb = fmaf(qf[j], fmaf(avb, wef[j], bf2f((u16)k8b[j])), pb);
            vea[j] = fmaf(ava, wef[j], bf2f((u16)v8a[j]));
            veb[j] = fmaf(avb, wef[j], bf2f((u16)v8b[j]));
        }
        pa += __shfl_xor(pa, 1); pb += __shfl_xor(pb, 1);
        pa += __shfl_xor(pa, 2); pb += __shfl_xor(pb, 2);
        float mn = fmaxf(mi, fmaxf(pa, pb));
        float fs = __expf(mi - mn);
        float pea = __expf(pa - mn);
        float peb = __expf(pb - mn);
        si = fmaf(si, fs, pea + peb);
        #pragma unroll
        for (int j = 0; j < 8; j++)
            a8[j] = fmaf(a8[j], fs, fmaf(pea, vea[j], peb * veb[j]));
        mi = mn;
    }
    if (i < re) {   // tail single edge
        int2 sa = csr[i];
        float av = __int_as_float(sa.y);
        const u16* sr = &qkvs[(size_t)sa.x * 512 + f0];
        bf16x8 k8 = *(const bf16x8*)(sr + 128);
        bf16x8 v8 = *(const bf16x8*)(sr + 256);
        float p = 0.f;
        float ve[8];
        #pragma unroll
        for (int j = 0; j < 8; j++) {
            p = fmaf(qf[j], fmaf(av, wef[j], bf2f((u16)k8[j])), p);
            ve[j] = fmaf(av, wef[j], bf2f((u16)v8[j]));
        }
        p += __shfl_xor(p, 1); p += __shfl_xor(p, 2);
        float mn = fmaxf(mi, p);
        float fs = __expf(mi - mn);
        float pe = __expf(p - mn);
        si = fmaf(si, fs, pe);
        #pragma unroll
        for (int j = 0; j < 8; j++) a8[j] = fmaf(a8[j], fs, pe * ve[j]);
        mi = mn;
    }
    // merge the 4 sub-streams (online-softmax state merge, xor 16 then 32)
    #pragma unroll
    for (int off = 16; off < 64; off <<= 1) {
        float mo = __shfl_xor(mi, off);
        float so = __shfl_xor(si, off);
        float mm = fmaxf(mi, mo);
        float f1 = __expf(mi - mm);
        float f2 = __expf(mo - mm);
        si = si * f1 + so * f2;
        #pragma unroll
        for (int j = 0; j < 8; j++) {
            float ao = __shfl_xor(a8[j], off);
            a8[j] = a8[j] * f1 + ao * f2;
        }
        mi = mm;
    }
    if (sub == 0) {
        float inv = 1.f / (si + 1e-16f);
        bf16x8 s8 = *(const bf16x8*)&qkvs[(size_t)dstn * 512 + 384 + f0];
        ushort4 p0, p1;
        float o[8];
        #pragma unroll
        for (int j = 0; j < 8; j++)
            o[j] = fmaxf(fmaf(a8[j], inv, bf2f((u16)s8[j])), 0.f);
        p0.x = f2bf(o[0]); p0.y = f2bf(o[1]); p0.z = f2bf(o[2]); p0.w = f2bf(o[3]);
        p1.x = f2bf(o[4]); p1.y = f2bf(o[5]); p1.z = f2bf(o[6]); p1.w = f2bf(o[7]);
        u16* hr = hout + (size_t)dstn * 128 + f0;
        *(ushort4*)hr = p0;
        *(ushort4*)(hr + 4) = p1;
    }
}

// ---------------- global mean pool (bf16 h input) ----------------
__global__ __launch_bounds__(256) void k_pool(
    const u16* __restrict__ h, const int* __restrict__ batch,
    float* __restrict__ gsum, float* __restrict__ gcnt)
{
    __shared__ float ssum[8 * 128];
    __shared__ float scnt[8];
    int t = threadIdx.x;
    for (int i = t; i < 8 * 128; i += 256) ssum[i] = 0.f;
    if (t < 8) scnt[t] = 0.f;
    __syncthreads();
    int f = t & 127, half = t >> 7;
    int per = (N_NODES + gridDim.x - 1) / gridDim.x;
    int lo = blockIdx.x * per;
    int hi = lo + per; if (hi > N_NODES) hi = N_NODES;
    float racc = 0.f; float rcnt = 0.f; int rg = -1;
    for (int n = lo + half; n < hi; n += 2) {
        int g = batch[n];
        if (g != rg) {
            if (rg >= 0) { atomicAdd(&ssum[rg * 128 + f], racc); if (f == 0) atomicAdd(&scnt[rg], rcnt); }
            rg = g; racc = 0.f; rcnt = 0.f;
        }
        racc += bf2f(h[(size_t)n * 128 + f]);
        rcnt += 1.f;
    }
    if (rg >= 0) { atomicAdd(&ssum[rg * 128 + f], racc); if (f == 0) atomicAdd(&scnt[rg], rcnt); }
    __syncthreads();
    for (int i = t; i < 8 * 128; i += 256) unsafeAtomicAdd(&gsum[i], ssum[i]);
    if (t < 8) unsafeAtomicAdd(&gcnt[t], scnt[t]);
}

__global__ void k_out(const float* __restrict__ gsum, const float* __restrict__ gcnt,
                      void* __restrict__ outp, const int* __restrict__ flag) {
    int fl = getflag(flag);
    int t = threadIdx.x;  // 1024
    float c = fmaxf(gcnt[t >> 7], 1.f);
    float v = gsum[t] / c;
    if (fl) ((float*)outp)[t] = v;
    else ((u16*)outp)[t] = f2bf(v);
}

extern "C" void kernel_launch(void* const* d_in, const int* in_sizes, int n_in,
                              void* d_out, int out_size, void* d_ws, size_t ws_size,
                              hipStream_t stream)
{
    (void)in_sizes; (void)n_in; (void)out_size; (void)ws_size;
    const void* x    = d_in[0];
    const int* ei    = (const int*)d_in[1];
    const void* ea   = d_in[2];
    const int* batch = (const int*)d_in[3];
    const void* w1   = d_in[4];
    const void* b1   = d_in[5];
    const void* lng  = d_in[6];
    const void* lnb  = d_in[7];
    const void* w2   = d_in[8];
    const void* b2   = d_in[9];
    const int* srcp = ei;
    const int* dstp = ei + N_EDGES;

    char* wsb = (char*)d_ws;
    size_t cur = 0;
    auto alloc = [&](size_t sz) -> void* {
        void* p = wsb + cur;
        cur += (sz + 255) & ~(size_t)255;
        return p;
    };
    u16*   y      = (u16*)  alloc((size_t)N_NODES * 128 * 2);   // bf16 lin1 output
    u16*   h1     = (u16*)  alloc((size_t)N_NODES * 128 * 2);   // bf16; reused as h3
    u16*   h2     = (u16*)  alloc((size_t)N_NODES * 128 * 2);   // bf16
    u16*   qkvs   = (u16*)  alloc((size_t)N_NODES * 512 * 2);
    int2*  csr    = (int2*) alloc((size_t)N_EDGES * 8);
    u16*   gt     = (u16*)  alloc(128 * 128 * 2);
    u16*   wcat1  = (u16*)  alloc(512 * 128 * 2);
    u16*   wcat2  = (u16*)  alloc(512 * 128 * 2);
    float* csum   = (float*)alloc(128 * 4);
    float* bwp    = (float*)alloc(128 * 4);
    u32*   w1pk   = (u32*)  alloc(64 * 4);
    float* bcat1  = (float*)alloc(512 * 4);
    float* bcat2  = (float*)alloc(512 * 4);
    int*   cntdeg = (int*)  alloc((size_t)N_NODES * 4);
    int*   rowst  = (int*)  alloc((size_t)(N_NODES + 1) * 4);
    int*   nxt    = (int*)  alloc((size_t)N_NODES * 4);
    float* gsum   = (float*)alloc((8 * 128 + 8) * 4);
    int*   dtflag = (int*)  alloc(256);
    u16*   h3 = h1;   // h1 is dead after first k_proj

    hipMemsetAsync(cntdeg, 0, (size_t)N_NODES * 4, stream);
    hipMemsetAsync(gsum, 0, (8 * 128 + 8) * 4, stream);

    k_detect<<<1, 256, 0, stream>>>((const u16*)x, dtflag);

    P8 pw; P8 pb;
    pw.s[0] = d_in[10]; pw.s[1] = d_in[12]; pw.s[2] = d_in[14]; pw.s[3] = d_in[17];
    pw.s[4] = d_in[19]; pw.s[5] = d_in[21]; pw.s[6] = d_in[23]; pw.s[7] = d_in[26];
    pb.s[0] = d_in[11]; pb.s[1] = d_in[13]; pb.s[2] = d_in[15]; pb.s[3] = d_in[18];
    pb.s[4] = d_in[20]; pb.s[5] = d_in[22]; pb.s[6] = d_in[24]; pb.s[7] = d_in[27];
    k_transpose8<<<512, 256, 0, stream>>>(pw, wcat1, wcat2, dtflag);
    k_bcat8<<<4, 256, 0, stream>>>(pb, bcat1, bcat2, dtflag);
    k_prep_w2<<<1, 128, 0, stream>>>(w2, lng, lnb, b2, w1, gt, csum, bwp, w1pk, dtflag);

    k_embed_lin1<<<782, 256, 0, stream>>>(x, w1, b1, y, dtflag);
    k_degree<<<3125, 256, 0, stream>>>(dstp, cntdeg);
    k_scan<<<1, 1024, 0, stream>>>(cntdeg, rowst, nxt);
    k_scatter<<<3125, 256, 0, stream>>>(dstp, srcp, ea, nxt, csr, dtflag);
    k_embed_edges<<<2048, 256, 0, stream>>>(y, csr, rowst, lng, lnb,
                                            gt, w1pk, csum, bwp, h1, dtflag);
    k_proj<<<782, 256, 0, stream>>>(h1, wcat1, bcat1, qkvs);
    k_attn<<<12500, 256, 0, stream>>>(qkvs, rowst, csr, d_in[16], h2, dtflag);
    k_proj<<<782, 256, 0, stream>>>(h2, wcat2, bcat2, qkvs);
    k_attn<<<12500, 256, 0, stream>>>(qkvs, rowst, csr, d_in[25], h3, dtflag);
    k_pool<<<128, 256, 0, stream>>>(h3, batch, gsum, gsum + 8 * 128);
    k_out<<<1, 1024, 0, stream>>>(gsum, gsum + 8 * 128, d_out, dtflag);
}